// Round 15
// baseline (281.203 us; speedup 1.0000x reference)
//
#include <hip/hip_runtime.h>
#include <math.h>

namespace {

constexpr int B = 8, C = 384, S = 1024;
constexpr int HID = 512, HEADS = 4, HD = 96, FFN = 1536;
constexpr int M = B * S;          // 8192 rows
constexpr int C3 = 3 * C;         // 1152
constexpr int K2C = 2 * C;        // 768 (agent K)
constexpr int FIXCAP = 4096;

using u16 = unsigned short;
using short8 = __attribute__((ext_vector_type(8))) short;
using short4 = __attribute__((ext_vector_type(4))) short;
using f32x4 = __attribute__((ext_vector_type(4))) float;
using u16x4 = __attribute__((ext_vector_type(4))) unsigned short;

__device__ inline u16 f2bf(float f) {
  unsigned int u = __builtin_bit_cast(unsigned int, f);
  u += 0x7fffu + ((u >> 16) & 1u);
  return (u16)(u >> 16);
}
__device__ inline float bf2f(u16 h) {
  unsigned int u = ((unsigned int)h) << 16;
  return __builtin_bit_cast(float, u);
}
__device__ inline unsigned int cvtpk(float a, float b) {  // [bf16(b)<<16 | bf16(a)]
  unsigned int r;
  asm("v_cvt_pk_bf16_f32 %0, %1, %2" : "=v"(r) : "v"(a), "v"(b));
  return r;
}

// ------- all weights -> bf16 in one dispatch; also zeroes fixup ctr ----
constexpr int N4_IN = 2 * C3 * C / 4;
constexpr int N4_OUT = 2 * C * C / 4;
constexpr int N4_F1 = 2 * FFN * C / 4;
constexpr int N4_F2 = 2 * C * FFN / 4;
constexpr int N4_W1 = HID * K2C / 4;
constexpr int N4_ALL = N4_IN + N4_OUT + N4_F1 + N4_F2 + N4_W1;

__global__ __launch_bounds__(256) void cvt_all(const float* __restrict__ in_w,
                                               const float* __restrict__ out_w,
                                               const float* __restrict__ f1,
                                               const float* __restrict__ f2,
                                               const float* __restrict__ w1,
                                               u16* __restrict__ dst,
                                               int* __restrict__ ctr) {
  int i = blockIdx.x * 256 + threadIdx.x;
  if (i == 0) ctr[0] = 0;
  if (i >= N4_ALL) return;
  const float* src;
  int off = i;
  if (i < N4_IN) {
    src = in_w;
  } else if (i < N4_IN + N4_OUT) {
    src = out_w; off = i - N4_IN;
  } else if (i < N4_IN + N4_OUT + N4_F1) {
    src = f1; off = i - N4_IN - N4_OUT;
  } else if (i < N4_IN + N4_OUT + N4_F1 + N4_F2) {
    src = f2; off = i - N4_IN - N4_OUT - N4_F1;
  } else {
    src = w1; off = i - N4_IN - N4_OUT - N4_F1 - N4_F2;
  }
  f32x4 v = reinterpret_cast<const f32x4*>(src)[off];
  u16x4 o;
#pragma unroll
  for (int j = 0; j < 4; ++j) o[j] = f2bf(v[j]);
  reinterpret_cast<u16x4*>(dst)[i] = o;
}

// ------- both transposes [C,S]->[S,C] in one dispatch, fused agent bf16 emit --
__global__ __launch_bounds__(256) void transpose_cs(const float* __restrict__ f_ir,
                                                    const float* __restrict__ f_vis,
                                                    float* __restrict__ x0,
                                                    u16* __restrict__ Ahi) {
  __shared__ float tile[32][33];
  int bz = blockIdx.z;
  int b = bz & 7, which = bz >> 3;
  const float* in = which ? f_vis : f_ir;
  float* out = x0 + (size_t)which * M * C;
  int coff = which ? C : 0;
  int s0 = blockIdx.x * 32, c0 = blockIdx.y * 32;
  const float* ip = in + (size_t)b * C * S;
  float* op = out + (size_t)b * S * C;
  int tx = threadIdx.x, ty = threadIdx.y;   // 32 x 8
#pragma unroll
  for (int i = 0; i < 32; i += 8)
    tile[ty + i][tx] = ip[(size_t)(c0 + ty + i) * S + s0 + tx];
  __syncthreads();
#pragma unroll
  for (int i = 0; i < 32; i += 8) {
    int s = s0 + ty + i;
    float v = tile[tx][ty + i];
    op[(size_t)s * C + c0 + tx] = v;
    Ahi[(size_t)(b * S + s) * K2C + coff + c0 + tx] = f2bf(v);
  }
}

// ---------------- bf16 MFMA GEMM helpers (swizzled global_load_lds) ----------
__device__ inline void stage_tile(const u16* __restrict__ g, int ldk,
                                  u16* lds, int tid) {
  int w = tid >> 6, l = tid & 63;
#pragma unroll
  for (int i = 0; i < 4; ++i) {
    int lin = i * 4096 + w * 1024 + l * 16;   // byte within 16KB tile
    int row = lin >> 7;                        // 128B per row (64 bf16)
    int slot = (lin >> 4) & 7;
    int k = (slot ^ (row & 7)) * 8;            // inverse-swizzled source
    const u16* gp = g + (size_t)row * ldk + k;
    u16* lp = lds + i * 2048 + w * 512;        // wave-uniform dest (elements)
    __builtin_amdgcn_global_load_lds(
        (const __attribute__((address_space(1))) unsigned int*)gp,
        (__attribute__((address_space(3))) unsigned int*)lp, 16, 0, 0);
  }
}

__device__ inline short8 frag_ld(const u16* lds, int row, int slot) {
  int s = slot ^ (row & 7);
  return *reinterpret_cast<const short8*>(lds + row * 64 + s * 8);
}

// out[M,N] = A[M,K](bf16) * W[N,K]^T(bf16); 128x128 tile, BK=64, 4 waves 2x2.
// MODE 0: +bias -> bf16. MODE 1: +bias, GELU -> bf16. MODE 2: +bias += fp32 xres.
// MODE 3: +bias, SiLU -> fp32 xres.
// mbound (nullable): device row bound; blocks with bm >= *mbound exit.
template <int MODE>
__global__ __launch_bounds__(256) void gemm_bf16(const u16* __restrict__ A,
                                                 const u16* __restrict__ W,
                                                 const float* __restrict__ bias,
                                                 float* __restrict__ xres,
                                                 u16* __restrict__ obf,
                                                 int N, int K,
                                                 int zsA, int zsW, int zsB, int zsO,
                                                 const int* __restrict__ mbound) {
  __shared__ u16 Asb[128 * 64];
  __shared__ u16 Wsb[128 * 64];
  int bn = blockIdx.x * 128, bm = blockIdx.y * 128;
  if (mbound && bm >= *mbound) return;
  int z = blockIdx.z;
  if (z) {
    A += (size_t)z * zsA;
    W += (size_t)z * zsW;
    bias += (size_t)z * zsB;
    if (MODE == 2 || MODE == 3) xres += (size_t)z * zsO;
    else obf += (size_t)z * zsO;
  }
  int tid = threadIdx.x;
  int wave = tid >> 6, lane = tid & 63, lo = lane & 15, hi = lane >> 4;
  int wr = wave >> 1, wc = wave & 1;
  const u16* Ag = A + (size_t)bm * K;
  const u16* Wg = W + (size_t)bn * K;
  f32x4 acc[4][4] = {};
  for (int k0 = 0; k0 < K; k0 += 64) {
    stage_tile(Ag + k0, K, Asb, tid);
    stage_tile(Wg + k0, K, Wsb, tid);
    __syncthreads();
#pragma unroll
    for (int ks = 0; ks < 2; ++ks) {
      short8 a[4], b[4];
#pragma unroll
      for (int mi = 0; mi < 4; ++mi) a[mi] = frag_ld(Asb, wr * 64 + mi * 16 + lo, ks * 4 + hi);
#pragma unroll
      for (int nj = 0; nj < 4; ++nj) b[nj] = frag_ld(Wsb, wc * 64 + nj * 16 + lo, ks * 4 + hi);
#pragma unroll
      for (int mi = 0; mi < 4; ++mi)
#pragma unroll
        for (int nj = 0; nj < 4; ++nj)
          acc[mi][nj] = __builtin_amdgcn_mfma_f32_16x16x32_bf16(a[mi], b[nj], acc[mi][nj], 0, 0, 0);
    }
    __syncthreads();
  }
  float bv[4];
#pragma unroll
  for (int nj = 0; nj < 4; ++nj) bv[nj] = bias[bn + wc * 64 + nj * 16 + lo];
#pragma unroll
  for (int mi = 0; mi < 4; ++mi) {
#pragma unroll
    for (int r = 0; r < 4; ++r) {
      int m = bm + wr * 64 + mi * 16 + hi * 4 + r;
#pragma unroll
      for (int nj = 0; nj < 4; ++nj) {
        int n = bn + wc * 64 + nj * 16 + lo;
        float v = acc[mi][nj][r] + bv[nj];
        size_t idx = (size_t)m * N + n;
        if (MODE == 0) {
          obf[idx] = f2bf(v);
        } else if (MODE == 1) {
          v = 0.5f * v * (1.f + erff(v * 0.70710678f));
          obf[idx] = f2bf(v);
        } else if (MODE == 2) {
          xres[idx] += v;
        } else {  // MODE 3
          xres[idx] = v / (1.f + expf(-v));
        }
      }
    }
  }
}

// ---------------- agent logit + threshold + ambiguity list ----------------
// Threshold 0.02: single-pass bf16 logit error rms ~1.4e-3 -> 14-sigma margin;
// all |logit| < 0.02 rows recomputed exactly in fp32 by fixup_kernel.
__global__ __launch_bounds__(64) void sel_kernel(const float* __restrict__ hidden,
                                                 const float* __restrict__ w2,
                                                 const float* __restrict__ b2,
                                                 int* __restrict__ sel,
                                                 int* __restrict__ ctr,
                                                 int* __restrict__ list) {
  int row = blockIdx.x, t = threadIdx.x;
  const float* hr = hidden + (size_t)row * HID;
  float s = 0.f;
#pragma unroll
  for (int i = 0; i < HID / 64; ++i) s += hr[t + i * 64] * w2[t + i * 64];
  for (int off = 32; off; off >>= 1) s += __shfl_down(s, off);
  if (t == 0) {
    float logit = s + b2[0];
    sel[row] = logit > 0.f ? 1 : 0;
    if (fabsf(logit) < 0.02f) {
      int idx = atomicAdd(ctr, 1);
      if (idx < FIXCAP) list[idx] = row;
    }
  }
}

// ---------------- exact fp32 recompute of ambiguous rows (coalesced) ----------
// One block per flagged row (grid-stride). Wave wv owns hidden units n=wv,wv+4,...
// For each n the 64 lanes split K: lane reads w1[n][j*256 + lane*4 .. +3]
// (3 fully-coalesced 1KB loads), butterfly-reduce gives all lanes the dot.
__global__ __launch_bounds__(256) void fixup_kernel(const float* __restrict__ x0,
                                                    const float* __restrict__ x1,
                                                    const float* __restrict__ w1,
                                                    const float* __restrict__ b1,
                                                    const float* __restrict__ w2,
                                                    const float* __restrict__ b2,
                                                    const int* __restrict__ ctr,
                                                    const int* __restrict__ list,
                                                    int* __restrict__ sel) {
  __shared__ float xs[K2C];
  __shared__ float red[4];
  int cnt = ctr[0];
  if (cnt > FIXCAP) cnt = FIXCAP;
  int tid = threadIdx.x;
  int lane = tid & 63, wv = tid >> 6;
  f32x4* xsv = reinterpret_cast<f32x4*>(xs);
  for (int ii = blockIdx.x; ii < cnt; ii += gridDim.x) {
    int row = list[ii];
    // stage xcat row vectorized: 192 f32x4 slots
    if (tid < 96) xsv[tid] = reinterpret_cast<const f32x4*>(x0 + (size_t)row * C)[tid];
    else if (tid < 192)
      xsv[tid] = reinterpret_cast<const f32x4*>(x1 + (size_t)row * C)[tid - 96];
    __syncthreads();
    f32x4 xv0 = xsv[lane], xv1 = xsv[64 + lane], xv2 = xsv[128 + lane];
    float partial = 0.f;
    for (int n = wv; n < HID; n += 4) {
      const f32x4* wr = reinterpret_cast<const f32x4*>(w1 + (size_t)n * K2C);
      f32x4 w0 = wr[lane], w1v = wr[64 + lane], w2v = wr[128 + lane];
      float d = 0.f;
#pragma unroll
      for (int j = 0; j < 4; ++j) {
        d = fmaf(w0[j], xv0[j], d);
        d = fmaf(w1v[j], xv1[j], d);
        d = fmaf(w2v[j], xv2[j], d);
      }
#pragma unroll
      for (int off = 32; off; off >>= 1) d += __shfl_xor(d, off);
      // every lane now holds the full dot for this n
      float acc = d + b1[n];
      acc = acc / (1.f + expf(-acc));  // SiLU
      partial = fmaf(acc, w2[n], partial);
    }
    // partial is identical across lanes of a wave
    if (lane == 0) red[wv] = partial;
    __syncthreads();
    if (tid == 0) {
      float logit = red[0] + red[1] + red[2] + red[3] + b2[0];
      sel[row] = logit > 0.f ? 1 : 0;
    }
    __syncthreads();
  }
}

// ---------------- per-batch exclusive prefix scan of sel ----------------
__global__ __launch_bounds__(256) void prefix_kernel(const int* __restrict__ sel,
                                                     int* __restrict__ pos,
                                                     int* __restrict__ nsel) {
  __shared__ int wsum[4];
  int b = blockIdx.x, tid = threadIdx.x;
  int lane = tid & 63, wv = tid >> 6;
  int v[4], lp[4];
  int tot = 0;
#pragma unroll
  for (int j = 0; j < 4; ++j) {
    v[j] = sel[b * S + tid * 4 + j];
    lp[j] = tot;
    tot += v[j];
  }
  int inc = tot;
#pragma unroll
  for (int off = 1; off < 64; off <<= 1) {
    int n = __shfl_up(inc, off);
    if (lane >= off) inc += n;
  }
  if (lane == 63) wsum[wv] = inc;
  __syncthreads();
  int wbase = 0;
#pragma unroll
  for (int w = 0; w < 4; ++w)
    if (w < wv) wbase += wsum[w];
  int ex = wbase + inc - tot;
#pragma unroll
  for (int j = 0; j < 4; ++j) pos[b * S + tid * 4 + j] = ex + lp[j];
  if (tid == 0) nsel[b] = wsum[0] + wsum[1] + wsum[2] + wsum[3];
}

// ---------------- per-batch 64-aligned compacted offsets ----------------
__global__ void boff_kernel(const int* __restrict__ nsel, int* __restrict__ coff) {
  if (threadIdx.x == 0) {
    int acc = 0;
    for (int b = 0; b < 8; ++b) {
      coff[b] = acc;
      acc += (nsel[b] + 63) & ~63;
    }
    coff[8] = acc;  // Mcp (64-aligned total compacted rows per stream)
  }
}

// ---------------- gather selected x rows into compacted xc -------------------
__global__ __launch_bounds__(64) void gather_x(const float* __restrict__ x0,
                                               const int* __restrict__ sel,
                                               const int* __restrict__ pos,
                                               const int* __restrict__ coff,
                                               float* __restrict__ xc) {
  int row = blockIdx.x;                 // 0..2M
  int bs = row & (M - 1);
  if (!sel[bs]) return;
  int strm = row >> 13, b = bs >> 10;
  int rc = coff[b] + pos[bs];
  const f32x4* src = reinterpret_cast<const f32x4*>(x0 + (size_t)row * C);
  f32x4* dst = reinterpret_cast<f32x4*>(xc + ((size_t)(strm * M) + rc) * C);
  int t = threadIdx.x;
  dst[t] = src[t];
  if (t < 32) dst[t + 64] = src[t + 64];
}

// ---------------- zero the per-batch pad rows of xc ----------------
__global__ __launch_bounds__(256) void zero_pad(const int* __restrict__ nsel,
                                                const int* __restrict__ coff,
                                                float* __restrict__ xc) {
  int z = blockIdx.x;                   // 16 = 2 streams x 8 batches
  int strm = z >> 3, b = z & 7;
  int ns = nsel[b];
  int npad = ((ns + 63) & ~63) - ns;
  float* base = xc + ((size_t)(strm * M) + coff[b] + ns) * C;
  int tot = npad * C;
  for (int i = threadIdx.x; i < tot; i += 256) base[i] = 0.f;
}

// ---------------- compacted LayerNorm -> bf16, one wave per row ----------------
__global__ __launch_bounds__(64) void ln_kernel(const float* __restrict__ x,
                                                const float* __restrict__ g_all,
                                                const float* __restrict__ b_all,
                                                u16* __restrict__ y,
                                                const int* __restrict__ coff) {
  int row = blockIdx.x, t = threadIdx.x;
  int strm = row >> 13, rc = row & (M - 1);
  if (rc >= coff[8]) return;
  const float* g = g_all + strm * C;
  const float* bt = b_all + strm * C;
  const float* xr = x + (size_t)row * C;
  float v[C / 64];
  float s = 0.f, s2 = 0.f;
#pragma unroll
  for (int i = 0; i < C / 64; ++i) {
    float a = xr[t + i * 64];
    v[i] = a;
    s += a;
    s2 += a * a;
  }
  for (int off = 32; off; off >>= 1) {
    s += __shfl_down(s, off);
    s2 += __shfl_down(s2, off);
  }
  s = __shfl(s, 0);
  s2 = __shfl(s2, 0);
  float mean = s / C;
  float var = s2 / C - mean * mean;
  float inv = rsqrtf(var + 1e-5f);
#pragma unroll
  for (int i = 0; i < C / 64; ++i) {
    int c = t + i * 64;
    y[(size_t)row * C + c] = f2bf((v[i] - mean) * inv * g[c] + bt[c]);
  }
}

// ---------------- flash MFMA attention v6 (fully compacted rows) --------------
__global__ __launch_bounds__(256) void attn_mfma(const u16* __restrict__ qkvc,
                                                 const int* __restrict__ nsel,
                                                 const int* __restrict__ coff,
                                                 u16* __restrict__ Dc) {
  __shared__ u16 Ks[64][104];
  __shared__ u16 Vt[96][72];

  int bq0 = blockIdx.x * 64;
  int bh2 = blockIdx.y;                  // 64 = 2 streams x 8 b x 4 h
  int strm = bh2 >> 5, bh = bh2 & 31;
  int b = bh >> 2, h = bh & 3;
  int ns = nsel[b];
  if (bq0 >= ns) return;
  int cb = coff[b];
  const u16* qbase = qkvc + ((size_t)(strm * M) + cb) * C3;
  int tid = threadIdx.x;
  int wave = tid >> 6, lane = tid & 63;
  int lo = lane & 15, g = lane >> 4;

  // Q fragments in registers, pre-scaled by 1/sqrt(HD)
  const float scale = 0.1020620726f;
  short8 bq[3];
  const u16* qrow = qbase + (size_t)(bq0 + wave * 16 + lo) * C3 + h * HD;
#pragma unroll
  for (int c = 0; c < 3; ++c) {
    short8 q = *reinterpret_cast<const short8*>(qrow + c * 32 + g * 8);
    short8 r;
#pragma unroll
    for (int e = 0; e < 8; ++e) r[e] = (short)f2bf(bf2f((u16)q[e]) * scale);
    bq[c] = r;
  }

  float m = -30.f, l = 0.f;
  f32x4 o[6] = {};
  int nt64 = (ns + 63) & ~63;

  for (int kt0 = 0; kt0 < nt64; kt0 += 64) {
    const u16* kbase = qbase + (size_t)kt0 * C3 + C + h * HD;
    const u16* vbase = qbase + (size_t)kt0 * C3 + 2 * C + h * HD;
#pragma unroll
    for (int i = 0; i < 3; ++i) {
      int idx = i * 256 + tid;
      int r = idx / 12, j = idx - r * 12;
      *reinterpret_cast<short8*>(&Ks[r][j * 8]) =
          *reinterpret_cast<const short8*>(kbase + (size_t)r * C3 + j * 8);
    }
#pragma unroll
    for (int i = 0; i < 3; ++i) {
      int idx = i * 256 + tid;
      int r = idx & 63, j = idx >> 6;
      short8 v = *reinterpret_cast<const short8*>(vbase + (size_t)r * C3 + j * 8);
#pragma unroll
      for (int e = 0; e < 8; ++e) Vt[j * 8 + e][r] = (u16)v[e];
    }
    __syncthreads();

    // QK^T: st[t4][r] = S[k=kt0+16t4+4g+r][q=lo]
    f32x4 st[4] = {};
    __builtin_amdgcn_s_setprio(1);
#pragma unroll
    for (int c = 0; c < 3; ++c)
#pragma unroll
      for (int t4 = 0; t4 < 4; ++t4) {
        short8 ak = *reinterpret_cast<const short8*>(&Ks[t4 * 16 + lo][c * 32 + g * 8]);
        st[t4] = __builtin_amdgcn_mfma_f32_16x16x32_bf16(ak, bq[c], st[t4], 0, 0, 0);
      }
    __builtin_amdgcn_s_setprio(0);

    float p[4][4];
    float pmax = -INFINITY;
#pragma unroll
    for (int t4 = 0; t4 < 4; ++t4)
#pragma unroll
      for (int r = 0; r < 4; ++r) p[t4][r] = st[t4][r];
    if (kt0 + 64 > ns) {  // tail tile: mask pad keys
#pragma unroll
      for (int t4 = 0; t4 < 4; ++t4)
#pragma unroll
        for (int r = 0; r < 4; ++r)
          if (kt0 + t4 * 16 + g * 4 + r >= ns) p[t4][r] = -1e9f;
    }
#pragma unroll
    for (int t4 = 0; t4 < 4; ++t4)
#pragma unroll
      for (int r = 0; r < 4; ++r) pmax = fmaxf(pmax, p[t4][r]);
    pmax = fmaxf(pmax, __shfl_xor(pmax, 16));
    pmax = fmaxf(pmax, __shfl_xor(pmax, 32));
    if (__any(pmax - m > 8.f)) {
      float mn = fmaxf(m, pmax);
      float sc = __expf(m - mn);
      m = mn;
      l *= sc;
#pragma unroll
      for (int dt = 0; dt < 6; ++dt)
#pragma unroll
        for (int r = 0; r < 4; ++r) o[dt][r] *= sc;
    }
    float ps = 0.f;
#pragma unroll
    for (int t4 = 0; t4 < 4; ++t4)
#pragma unroll
      for (int r = 0; r < 4; ++r) {
        float e = __expf(p[t4][r] - m);
        p[t4][r] = e;
        ps += e;
      }
    ps += __shfl_xor(ps, 16);
    ps += __shfl_xor(ps, 32);
    l += ps;

    // pack P -> bf16 B-fragments; slot e<4: k=32h2+4g+e, e>=4: k=32h2+16+4g+(e-4)
    short8 bp[2];
#pragma unroll
    for (int h2 = 0; h2 < 2; ++h2) {
      union { short8 s8; unsigned int u[4]; } u_;
      u_.u[0] = cvtpk(p[2 * h2][0], p[2 * h2][1]);
      u_.u[1] = cvtpk(p[2 * h2][2], p[2 * h2][3]);
      u_.u[2] = cvtpk(p[2 * h2 + 1][0], p[2 * h2 + 1][1]);
      u_.u[3] = cvtpk(p[2 * h2 + 1][2], p[2 * h2 + 1][3]);
      bp[h2] = u_.s8;
    }

    // PV: A = V^T with the same k-slot permutation
    __builtin_amdgcn_s_setprio(1);
#pragma unroll
    for (int dt = 0; dt < 6; ++dt)
#pragma unroll
      for (int h2 = 0; h2 < 2; ++h2) {
        union { short8 s8; short4 s4[2]; } a_;
        a_.s4[0] = *reinterpret_cast<const short4*>(&Vt[dt * 16 + lo][h2 * 32 + g * 4]);
        a_.s4[1] = *reinterpret_cast<const short4*>(&Vt[dt * 16 + lo][h2 * 32 + 16 + g * 4]);
        o[dt] = __builtin_amdgcn_mfma_f32_16x16x32_bf16(a_.s8, bp[h2], o[dt], 0, 0, 0);
      }
    __builtin_amdgcn_s_setprio(0);
    __syncthreads();
  }

  float inv = 1.f / l;
  size_t orow = ((size_t)(strm * M) + cb + bq0 + wave * 16 + lo) * C + h * HD;
#pragma unroll
  for (int dt = 0; dt < 6; ++dt)
#pragma unroll
    for (int r = 0; r < 4; ++r)
      Dc[orow + dt * 16 + g * 4 + r] = f2bf(o[dt][r] * inv);
}

// ---------------- final scatter with compaction indirection ----------------
__global__ __launch_bounds__(256) void final_kernel(const float* __restrict__ xc,
                                                    const int* __restrict__ sel,
                                                    const int* __restrict__ pos,
                                                    const int* __restrict__ coff,
                                                    const float* __restrict__ f_ir,
                                                    const float* __restrict__ f_vis,
                                                    float* __restrict__ out) {
  __shared__ float tile[32][33];
  int b = blockIdx.z;
  int s0 = blockIdx.x * 32, c0 = blockIdx.y * 32;
  int tx = threadIdx.x, ty = threadIdx.y;  // 32 x 8
  const int* selb = sel + b * S;
  const int* posb = pos + b * S;
  int cb = coff[b];
#pragma unroll
  for (int i = 0; i < 32; i += 8) {
    int s = s0 + ty + i;
    if (selb[s]) {
      size_t rc = cb + posb[s];
      tile[ty + i][tx] = xc[rc * C + c0 + tx] + xc[((size_t)M + rc) * C + c0 + tx];
    }
  }
  __syncthreads();
#pragma unroll
  for (int i = 0; i < 32; i += 8) {
    int c = c0 + ty + i, s = s0 + tx;
    size_t idx = ((size_t)(b * C + c)) * S + s;
    float v = selb[s] ? tile[tx][ty + i] : (f_ir[idx] + f_vis[idx]);
    out[idx] = v;
  }
}

}  // namespace

extern "C" void kernel_launch(void* const* d_in, const int* in_sizes, int n_in,
                              void* d_out, int out_size, void* d_ws, size_t ws_size,
                              hipStream_t stream) {
  const float* f_ir = (const float*)d_in[0];
  const float* f_vis = (const float*)d_in[1];
  const float* agent_w1 = (const float*)d_in[2];
  const float* agent_b1 = (const float*)d_in[3];
  const float* agent_w2 = (const float*)d_in[4];
  const float* agent_b2 = (const float*)d_in[5];
  const float* norm_g = (const float*)d_in[6];
  const float* norm_b = (const float*)d_in[7];
  const float* in_w = (const float*)d_in[8];
  const float* in_b = (const float*)d_in[9];
  const float* out_w = (const float*)d_in[10];
  const float* out_b = (const float*)d_in[11];
  const float* ffn_w1 = (const float*)d_in[12];
  const float* ffn_b1 = (const float*)d_in[13];
  const float* ffn_w2 = (const float*)d_in[14];
  const float* ffn_b2 = (const float*)d_in[15];
  float* out = (float*)d_out;

  constexpr size_t MS = (size_t)M * C;
  float* ws = (float*)d_ws;
  float* x0 = ws;                                  // fp32 [2M,C] full rows
  float* xc = x0 + 2 * MS;                         // fp32 [2M,C] compacted residual
  u16* Hc = (u16*)(xc + 2 * MS);                   // [2M,FFN] region (hosts aliases)
  u16* wb_in = Hc + (size_t)2 * M * FFN;           // 2*C3*C
  u16* wb_out = wb_in + 2 * C3 * C;                // 2*C*C
  u16* wb_f1 = wb_out + 2 * C * C;                 // 2*FFN*C
  u16* wb_f2 = wb_f1 + 2 * FFN * C;                // 2*C*FFN
  u16* w1b = wb_f2 + 2 * C * FFN;                  // HID*K2C
  int* sel = (int*)(w1b + HID * K2C);
  int* ctr = sel + M;
  int* fixlist = ctr + 1;
  int* pos = fixlist + FIXCAP;                     // [8][1024]
  int* nsel = pos + M;                             // [8]
  int* coff = nsel + 8;                            // [9]; coff[8] = Mcp
  // aliases inside Hc region (each dead before its successor is written):
  u16* Ahi = Hc;                                   // [M,768] agent act (dead after agent gemm)
  float* hiddenF = (float*)(Hc + (size_t)M * 768); // [M,HID] fp32 (dead after sel/fixup)
  u16* qkvc = Hc;                                  // [2M,C3] compacted QKV (dead before FFN1)
  u16* Dc = (u16*)x0;                              // [2M,C] bf16 (aliases x0 after gather)
  float* x1 = x0 + MS;

  // 0) all weights -> bf16 in one dispatch (also zeroes fixup ctr)
  cvt_all<<<(N4_ALL + 255) / 256, 256, 0, stream>>>(in_w, out_w, ffn_w1, ffn_w2,
                                                    agent_w1, wb_in, ctr);

  // 1) both transposes in one dispatch (fused agent bf16 activation emit)
  transpose_cs<<<dim3(S / 32, C / 32, 2 * B), dim3(32, 8), 0, stream>>>(
      f_ir, f_vis, x0, Ahi);

  // 2) agent hidden: single-pass bf16 MFMA + SiLU (fixup covers rounding)
  gemm_bf16<3><<<dim3(HID / 128, M / 128), 256, 0, stream>>>(
      Ahi, w1b, agent_b1, hiddenF, nullptr, HID, K2C, 0, 0, 0, 0, nullptr);

  // 3) selection mask + exact fp32 fixup + compaction metadata
  sel_kernel<<<M, 64, 0, stream>>>(hiddenF, agent_w2, agent_b2, sel, ctr, fixlist);
  fixup_kernel<<<304, 256, 0, stream>>>(x0, x1, agent_w1, agent_b1, agent_w2,
                                        agent_b2, ctr, fixlist, sel);
  prefix_kernel<<<B, 256, 0, stream>>>(sel, pos, nsel);
  boff_kernel<<<1, 64, 0, stream>>>(nsel, coff);

  // 4) gather selected rows -> compacted residual xc (pad rows zeroed)
  gather_x<<<2 * M, 64, 0, stream>>>(x0, sel, pos, coff, xc);
  zero_pad<<<16, 256, 0, stream>>>(nsel, coff, xc);

  // 5) compacted mixer, both streams z-batched (early-exit beyond coff[8])
  ln_kernel<<<2 * M, 64, 0, stream>>>(xc, norm_g, norm_b, Dc, coff);
  gemm_bf16<0><<<dim3(C3 / 128, M / 128, 2), 256, 0, stream>>>(
      Dc, wb_in, in_b, nullptr, qkvc, C3, C, M * C, C3 * C, C3, M * C3, coff + 8);
  attn_mfma<<<dim3(S / 64, B * HEADS * 2), 256, 0, stream>>>(qkvc, nsel, coff, Dc);
  gemm_bf16<2><<<dim3(C / 128, M / 128, 2), 256, 0, stream>>>(
      Dc, wb_out, out_b, xc, nullptr, C, C, M * C, C * C, C, M * C, coff + 8);
  ln_kernel<<<2 * M, 64, 0, stream>>>(xc, norm_g, norm_b, Dc, coff);
  gemm_bf16<1><<<dim3(FFN / 128, M / 128, 2), 256, 0, stream>>>(
      Dc, wb_f1, ffn_b1, nullptr, Hc, FFN, C, M * C, FFN * C, FFN, M * FFN, coff + 8);
  gemm_bf16<2><<<dim3(C / 128, M / 128, 2), 256, 0, stream>>>(
      Hc, wb_f2, ffn_b2, xc, nullptr, C, FFN, M * FFN, C * FFN, C, M * C, coff + 8);

  // 6) final scatter back to [B,C,H,W]
  final_kernel<<<dim3(S / 32, C / 32, B), dim3(32, 8), 0, stream>>>(
      xc, sel, pos, coff, f_ir, f_vis, out);
}

// Round 16
// 242.898 us; speedup vs baseline: 1.1577x; 1.1577x over previous
//
#include <hip/hip_runtime.h>
#include <math.h>

namespace {

constexpr int B = 8, C = 384, S = 1024;
constexpr int HID = 512, HEADS = 4, HD = 96, FFN = 1536;
constexpr int M = B * S;          // 8192 rows
constexpr int C3 = 3 * C;         // 1152
constexpr int K2C = 2 * C;        // 768 (agent K)
constexpr int FIXCAP = 4096;

using u16 = unsigned short;
using short8 = __attribute__((ext_vector_type(8))) short;
using short4 = __attribute__((ext_vector_type(4))) short;
using f32x4 = __attribute__((ext_vector_type(4))) float;
using u16x4 = __attribute__((ext_vector_type(4))) unsigned short;

__device__ inline u16 f2bf(float f) {
  unsigned int u = __builtin_bit_cast(unsigned int, f);
  u += 0x7fffu + ((u >> 16) & 1u);
  return (u16)(u >> 16);
}
__device__ inline float bf2f(u16 h) {
  unsigned int u = ((unsigned int)h) << 16;
  return __builtin_bit_cast(float, u);
}
__device__ inline unsigned int cvtpk(float a, float b) {  // [bf16(b)<<16 | bf16(a)]
  unsigned int r;
  asm("v_cvt_pk_bf16_f32 %0, %1, %2" : "=v"(r) : "v"(a), "v"(b));
  return r;
}

// ------- all weights -> bf16 in one dispatch; also zeroes fixup ctr ----
constexpr int N4_IN = 2 * C3 * C / 4;
constexpr int N4_OUT = 2 * C * C / 4;
constexpr int N4_F1 = 2 * FFN * C / 4;
constexpr int N4_F2 = 2 * C * FFN / 4;
constexpr int N4_W1 = HID * K2C / 4;
constexpr int N4_ALL = N4_IN + N4_OUT + N4_F1 + N4_F2 + N4_W1;

__global__ __launch_bounds__(256) void cvt_all(const float* __restrict__ in_w,
                                               const float* __restrict__ out_w,
                                               const float* __restrict__ f1,
                                               const float* __restrict__ f2,
                                               const float* __restrict__ w1,
                                               u16* __restrict__ dst,
                                               int* __restrict__ ctr) {
  int i = blockIdx.x * 256 + threadIdx.x;
  if (i == 0) ctr[0] = 0;
  if (i >= N4_ALL) return;
  const float* src;
  int off = i;
  if (i < N4_IN) {
    src = in_w;
  } else if (i < N4_IN + N4_OUT) {
    src = out_w; off = i - N4_IN;
  } else if (i < N4_IN + N4_OUT + N4_F1) {
    src = f1; off = i - N4_IN - N4_OUT;
  } else if (i < N4_IN + N4_OUT + N4_F1 + N4_F2) {
    src = f2; off = i - N4_IN - N4_OUT - N4_F1;
  } else {
    src = w1; off = i - N4_IN - N4_OUT - N4_F1 - N4_F2;
  }
  f32x4 v = reinterpret_cast<const f32x4*>(src)[off];
  u16x4 o;
#pragma unroll
  for (int j = 0; j < 4; ++j) o[j] = f2bf(v[j]);
  reinterpret_cast<u16x4*>(dst)[i] = o;
}

// ------- both transposes [C,S]->[S,C] in one dispatch, fused agent bf16 emit --
__global__ __launch_bounds__(256) void transpose_cs(const float* __restrict__ f_ir,
                                                    const float* __restrict__ f_vis,
                                                    float* __restrict__ x0,
                                                    u16* __restrict__ Ahi) {
  __shared__ float tile[32][33];
  int bz = blockIdx.z;
  int b = bz & 7, which = bz >> 3;
  const float* in = which ? f_vis : f_ir;
  float* out = x0 + (size_t)which * M * C;
  int coff = which ? C : 0;
  int s0 = blockIdx.x * 32, c0 = blockIdx.y * 32;
  const float* ip = in + (size_t)b * C * S;
  float* op = out + (size_t)b * S * C;
  int tx = threadIdx.x, ty = threadIdx.y;   // 32 x 8
#pragma unroll
  for (int i = 0; i < 32; i += 8)
    tile[ty + i][tx] = ip[(size_t)(c0 + ty + i) * S + s0 + tx];
  __syncthreads();
#pragma unroll
  for (int i = 0; i < 32; i += 8) {
    int s = s0 + ty + i;
    float v = tile[tx][ty + i];
    op[(size_t)s * C + c0 + tx] = v;
    Ahi[(size_t)(b * S + s) * K2C + coff + c0 + tx] = f2bf(v);
  }
}

// ---------------- bf16 MFMA GEMM helpers (swizzled global_load_lds) ----------
__device__ inline void stage_tile(const u16* __restrict__ g, int ldk,
                                  u16* lds, int tid) {
  int w = tid >> 6, l = tid & 63;
#pragma unroll
  for (int i = 0; i < 4; ++i) {
    int lin = i * 4096 + w * 1024 + l * 16;   // byte within 16KB tile
    int row = lin >> 7;                        // 128B per row (64 bf16)
    int slot = (lin >> 4) & 7;
    int k = (slot ^ (row & 7)) * 8;            // inverse-swizzled source
    const u16* gp = g + (size_t)row * ldk + k;
    u16* lp = lds + i * 2048 + w * 512;        // wave-uniform dest (elements)
    __builtin_amdgcn_global_load_lds(
        (const __attribute__((address_space(1))) unsigned int*)gp,
        (__attribute__((address_space(3))) unsigned int*)lp, 16, 0, 0);
  }
}

__device__ inline short8 frag_ld(const u16* lds, int row, int slot) {
  int s = slot ^ (row & 7);
  return *reinterpret_cast<const short8*>(lds + row * 64 + s * 8);
}

// out[M,N] = A[M,K](bf16) * W[N,K]^T(bf16); 128x128 tile, BK=64, 4 waves 2x2.
// MODE 0: +bias -> bf16. MODE 1: +bias, GELU -> bf16. MODE 2: +bias += fp32 xres.
// MODE 3: +bias, SiLU -> fp32 xres.
// mbound (nullable): device row bound; blocks with bm >= *mbound exit.
template <int MODE>
__global__ __launch_bounds__(256) void gemm_bf16(const u16* __restrict__ A,
                                                 const u16* __restrict__ W,
                                                 const float* __restrict__ bias,
                                                 float* __restrict__ xres,
                                                 u16* __restrict__ obf,
                                                 int N, int K,
                                                 int zsA, int zsW, int zsB, int zsO,
                                                 const int* __restrict__ mbound) {
  __shared__ u16 Asb[128 * 64];
  __shared__ u16 Wsb[128 * 64];
  int bn = blockIdx.x * 128, bm = blockIdx.y * 128;
  if (mbound && bm >= *mbound) return;
  int z = blockIdx.z;
  if (z) {
    A += (size_t)z * zsA;
    W += (size_t)z * zsW;
    bias += (size_t)z * zsB;
    if (MODE == 2 || MODE == 3) xres += (size_t)z * zsO;
    else obf += (size_t)z * zsO;
  }
  int tid = threadIdx.x;
  int wave = tid >> 6, lane = tid & 63, lo = lane & 15, hi = lane >> 4;
  int wr = wave >> 1, wc = wave & 1;
  const u16* Ag = A + (size_t)bm * K;
  const u16* Wg = W + (size_t)bn * K;
  f32x4 acc[4][4] = {};
  for (int k0 = 0; k0 < K; k0 += 64) {
    stage_tile(Ag + k0, K, Asb, tid);
    stage_tile(Wg + k0, K, Wsb, tid);
    __syncthreads();
#pragma unroll
    for (int ks = 0; ks < 2; ++ks) {
      short8 a[4], b[4];
#pragma unroll
      for (int mi = 0; mi < 4; ++mi) a[mi] = frag_ld(Asb, wr * 64 + mi * 16 + lo, ks * 4 + hi);
#pragma unroll
      for (int nj = 0; nj < 4; ++nj) b[nj] = frag_ld(Wsb, wc * 64 + nj * 16 + lo, ks * 4 + hi);
#pragma unroll
      for (int mi = 0; mi < 4; ++mi)
#pragma unroll
        for (int nj = 0; nj < 4; ++nj)
          acc[mi][nj] = __builtin_amdgcn_mfma_f32_16x16x32_bf16(a[mi], b[nj], acc[mi][nj], 0, 0, 0);
    }
    __syncthreads();
  }
  float bv[4];
#pragma unroll
  for (int nj = 0; nj < 4; ++nj) bv[nj] = bias[bn + wc * 64 + nj * 16 + lo];
#pragma unroll
  for (int mi = 0; mi < 4; ++mi) {
#pragma unroll
    for (int r = 0; r < 4; ++r) {
      int m = bm + wr * 64 + mi * 16 + hi * 4 + r;
#pragma unroll
      for (int nj = 0; nj < 4; ++nj) {
        int n = bn + wc * 64 + nj * 16 + lo;
        float v = acc[mi][nj][r] + bv[nj];
        size_t idx = (size_t)m * N + n;
        if (MODE == 0) {
          obf[idx] = f2bf(v);
        } else if (MODE == 1) {
          v = 0.5f * v * (1.f + erff(v * 0.70710678f));
          obf[idx] = f2bf(v);
        } else if (MODE == 2) {
          xres[idx] += v;
        } else {  // MODE 3
          xres[idx] = v / (1.f + expf(-v));
        }
      }
    }
  }
}

// ---------------- agent logit + threshold + ambiguity list ----------------
// Threshold 0.02: single-pass bf16 logit error rms ~1.4e-3 -> 14-sigma margin;
// all |logit| < 0.02 rows recomputed exactly in fp32 by fixup_part/finish.
__global__ __launch_bounds__(64) void sel_kernel(const float* __restrict__ hidden,
                                                 const float* __restrict__ w2,
                                                 const float* __restrict__ b2,
                                                 int* __restrict__ sel,
                                                 int* __restrict__ ctr,
                                                 int* __restrict__ list) {
  int row = blockIdx.x, t = threadIdx.x;
  const float* hr = hidden + (size_t)row * HID;
  float s = 0.f;
#pragma unroll
  for (int i = 0; i < HID / 64; ++i) s += hr[t + i * 64] * w2[t + i * 64];
  for (int off = 32; off; off >>= 1) s += __shfl_down(s, off);
  if (t == 0) {
    float logit = s + b2[0];
    sel[row] = logit > 0.f ? 1 : 0;
    if (fabsf(logit) < 0.02f) {
      int idx = atomicAdd(ctr, 1);
      if (idx < FIXCAP) list[idx] = row;
    }
  }
}

// ------- fixup stage 1: per-(flagged row, 64-unit chunk) partial logit -------
// Grid-stride over cnt*8 items. Thread = (unit, K-quarter): 48 f32x4 loads +
// 192 FMA, 2-step shuffle merge, SiLU*w2 on q==0 lane, block reduce.
__global__ __launch_bounds__(256) void fixup_part(const float* __restrict__ x0,
                                                  const float* __restrict__ x1,
                                                  const float* __restrict__ w1,
                                                  const float* __restrict__ b1,
                                                  const float* __restrict__ w2,
                                                  const int* __restrict__ ctr,
                                                  const int* __restrict__ list,
                                                  float* __restrict__ part) {
  __shared__ float xs[K2C];
  __shared__ float red[4];
  int cnt = ctr[0];
  if (cnt > FIXCAP) cnt = FIXCAP;
  int items = cnt * 8;
  int tid = threadIdx.x;
  f32x4* xsv = reinterpret_cast<f32x4*>(xs);
  for (int w = blockIdx.x; w < items; w += gridDim.x) {
    int ii = w >> 3, chunk = w & 7;
    int row = list[ii];
    if (tid < 96) xsv[tid] = reinterpret_cast<const f32x4*>(x0 + (size_t)row * C)[tid];
    else if (tid < 192)
      xsv[tid] = reinterpret_cast<const f32x4*>(x1 + (size_t)row * C)[tid - 96];
    __syncthreads();
    int n = chunk * 64 + (tid >> 2);   // hidden unit
    int q = tid & 3;                    // K quarter
    const f32x4* wr = reinterpret_cast<const f32x4*>(w1 + (size_t)n * K2C) + q * 48;
    const f32x4* xq = xsv + q * 48;
    float a0 = 0.f, a1 = 0.f, a2 = 0.f, a3 = 0.f;
#pragma unroll 12
    for (int k = 0; k < 48; ++k) {
      f32x4 wv = wr[k], xv = xq[k];
      a0 = fmaf(wv[0], xv[0], a0);
      a1 = fmaf(wv[1], xv[1], a1);
      a2 = fmaf(wv[2], xv[2], a2);
      a3 = fmaf(wv[3], xv[3], a3);
    }
    float d = (a0 + a1) + (a2 + a3);
    d += __shfl_xor(d, 1);
    d += __shfl_xor(d, 2);
    float pl = 0.f;
    if (q == 0) {
      float acc = d + b1[n];
      acc = acc / (1.f + expf(-acc));  // SiLU
      pl = acc * w2[n];
    }
    for (int off = 32; off; off >>= 1) pl += __shfl_down(pl, off);
    if ((tid & 63) == 0) red[tid >> 6] = pl;
    __syncthreads();
    if (tid == 0) part[w] = red[0] + red[1] + red[2] + red[3];
    __syncthreads();
  }
}

// ------- fixup stage 2: deterministic 8-way sum + sign decision -------
__global__ __launch_bounds__(64) void fixup_finish(const float* __restrict__ part,
                                                   const float* __restrict__ b2,
                                                   const int* __restrict__ ctr,
                                                   const int* __restrict__ list,
                                                   int* __restrict__ sel) {
  int ii = blockIdx.x * 64 + threadIdx.x;
  int cnt = ctr[0];
  if (cnt > FIXCAP) cnt = FIXCAP;
  if (ii >= cnt) return;
  float s = b2[0];
#pragma unroll
  for (int j = 0; j < 8; ++j) s += part[ii * 8 + j];
  sel[list[ii]] = s > 0.f ? 1 : 0;
}

// ---------------- per-batch exclusive prefix scan of sel ----------------
__global__ __launch_bounds__(256) void prefix_kernel(const int* __restrict__ sel,
                                                     int* __restrict__ pos,
                                                     int* __restrict__ nsel) {
  __shared__ int wsum[4];
  int b = blockIdx.x, tid = threadIdx.x;
  int lane = tid & 63, wv = tid >> 6;
  int v[4], lp[4];
  int tot = 0;
#pragma unroll
  for (int j = 0; j < 4; ++j) {
    v[j] = sel[b * S + tid * 4 + j];
    lp[j] = tot;
    tot += v[j];
  }
  int inc = tot;
#pragma unroll
  for (int off = 1; off < 64; off <<= 1) {
    int n = __shfl_up(inc, off);
    if (lane >= off) inc += n;
  }
  if (lane == 63) wsum[wv] = inc;
  __syncthreads();
  int wbase = 0;
#pragma unroll
  for (int w = 0; w < 4; ++w)
    if (w < wv) wbase += wsum[w];
  int ex = wbase + inc - tot;
#pragma unroll
  for (int j = 0; j < 4; ++j) pos[b * S + tid * 4 + j] = ex + lp[j];
  if (tid == 0) nsel[b] = wsum[0] + wsum[1] + wsum[2] + wsum[3];
}

// ---------------- per-batch 64-aligned compacted offsets ----------------
__global__ void boff_kernel(const int* __restrict__ nsel, int* __restrict__ coff) {
  if (threadIdx.x == 0) {
    int acc = 0;
    for (int b = 0; b < 8; ++b) {
      coff[b] = acc;
      acc += (nsel[b] + 63) & ~63;
    }
    coff[8] = acc;  // Mcp (64-aligned total compacted rows per stream)
  }
}

// ---------------- gather selected x rows into compacted xc -------------------
__global__ __launch_bounds__(64) void gather_x(const float* __restrict__ x0,
                                               const int* __restrict__ sel,
                                               const int* __restrict__ pos,
                                               const int* __restrict__ coff,
                                               float* __restrict__ xc) {
  int row = blockIdx.x;                 // 0..2M
  int bs = row & (M - 1);
  if (!sel[bs]) return;
  int strm = row >> 13, b = bs >> 10;
  int rc = coff[b] + pos[bs];
  const f32x4* src = reinterpret_cast<const f32x4*>(x0 + (size_t)row * C);
  f32x4* dst = reinterpret_cast<f32x4*>(xc + ((size_t)(strm * M) + rc) * C);
  int t = threadIdx.x;
  dst[t] = src[t];
  if (t < 32) dst[t + 64] = src[t + 64];
}

// ---------------- zero the per-batch pad rows of xc ----------------
__global__ __launch_bounds__(256) void zero_pad(const int* __restrict__ nsel,
                                                const int* __restrict__ coff,
                                                float* __restrict__ xc) {
  int z = blockIdx.x;                   // 16 = 2 streams x 8 batches
  int strm = z >> 3, b = z & 7;
  int ns = nsel[b];
  int npad = ((ns + 63) & ~63) - ns;
  float* base = xc + ((size_t)(strm * M) + coff[b] + ns) * C;
  int tot = npad * C;
  for (int i = threadIdx.x; i < tot; i += 256) base[i] = 0.f;
}

// ---------------- compacted LayerNorm -> bf16, one wave per row ----------------
__global__ __launch_bounds__(64) void ln_kernel(const float* __restrict__ x,
                                                const float* __restrict__ g_all,
                                                const float* __restrict__ b_all,
                                                u16* __restrict__ y,
                                                const int* __restrict__ coff) {
  int row = blockIdx.x, t = threadIdx.x;
  int strm = row >> 13, rc = row & (M - 1);
  if (rc >= coff[8]) return;
  const float* g = g_all + strm * C;
  const float* bt = b_all + strm * C;
  const float* xr = x + (size_t)row * C;
  float v[C / 64];
  float s = 0.f, s2 = 0.f;
#pragma unroll
  for (int i = 0; i < C / 64; ++i) {
    float a = xr[t + i * 64];
    v[i] = a;
    s += a;
    s2 += a * a;
  }
  for (int off = 32; off; off >>= 1) {
    s += __shfl_down(s, off);
    s2 += __shfl_down(s2, off);
  }
  s = __shfl(s, 0);
  s2 = __shfl(s2, 0);
  float mean = s / C;
  float var = s2 / C - mean * mean;
  float inv = rsqrtf(var + 1e-5f);
#pragma unroll
  for (int i = 0; i < C / 64; ++i) {
    int c = t + i * 64;
    y[(size_t)row * C + c] = f2bf((v[i] - mean) * inv * g[c] + bt[c]);
  }
}

// ---------------- flash MFMA attention v6 (fully compacted rows) --------------
__global__ __launch_bounds__(256) void attn_mfma(const u16* __restrict__ qkvc,
                                                 const int* __restrict__ nsel,
                                                 const int* __restrict__ coff,
                                                 u16* __restrict__ Dc) {
  __shared__ u16 Ks[64][104];
  __shared__ u16 Vt[96][72];

  int bq0 = blockIdx.x * 64;
  int bh2 = blockIdx.y;                  // 64 = 2 streams x 8 b x 4 h
  int strm = bh2 >> 5, bh = bh2 & 31;
  int b = bh >> 2, h = bh & 3;
  int ns = nsel[b];
  if (bq0 >= ns) return;
  int cb = coff[b];
  const u16* qbase = qkvc + ((size_t)(strm * M) + cb) * C3;
  int tid = threadIdx.x;
  int wave = tid >> 6, lane = tid & 63;
  int lo = lane & 15, g = lane >> 4;

  // Q fragments in registers, pre-scaled by 1/sqrt(HD)
  const float scale = 0.1020620726f;
  short8 bq[3];
  const u16* qrow = qbase + (size_t)(bq0 + wave * 16 + lo) * C3 + h * HD;
#pragma unroll
  for (int c = 0; c < 3; ++c) {
    short8 q = *reinterpret_cast<const short8*>(qrow + c * 32 + g * 8);
    short8 r;
#pragma unroll
    for (int e = 0; e < 8; ++e) r[e] = (short)f2bf(bf2f((u16)q[e]) * scale);
    bq[c] = r;
  }

  float m = -30.f, l = 0.f;
  f32x4 o[6] = {};
  int nt64 = (ns + 63) & ~63;

  for (int kt0 = 0; kt0 < nt64; kt0 += 64) {
    const u16* kbase = qbase + (size_t)kt0 * C3 + C + h * HD;
    const u16* vbase = qbase + (size_t)kt0 * C3 + 2 * C + h * HD;
#pragma unroll
    for (int i = 0; i < 3; ++i) {
      int idx = i * 256 + tid;
      int r = idx / 12, j = idx - r * 12;
      *reinterpret_cast<short8*>(&Ks[r][j * 8]) =
          *reinterpret_cast<const short8*>(kbase + (size_t)r * C3 + j * 8);
    }
#pragma unroll
    for (int i = 0; i < 3; ++i) {
      int idx = i * 256 + tid;
      int r = idx & 63, j = idx >> 6;
      short8 v = *reinterpret_cast<const short8*>(vbase + (size_t)r * C3 + j * 8);
#pragma unroll
      for (int e = 0; e < 8; ++e) Vt[j * 8 + e][r] = (u16)v[e];
    }
    __syncthreads();

    // QK^T: st[t4][r] = S[k=kt0+16t4+4g+r][q=lo]
    f32x4 st[4] = {};
    __builtin_amdgcn_s_setprio(1);
#pragma unroll
    for (int c = 0; c < 3; ++c)
#pragma unroll
      for (int t4 = 0; t4 < 4; ++t4) {
        short8 ak = *reinterpret_cast<const short8*>(&Ks[t4 * 16 + lo][c * 32 + g * 8]);
        st[t4] = __builtin_amdgcn_mfma_f32_16x16x32_bf16(ak, bq[c], st[t4], 0, 0, 0);
      }
    __builtin_amdgcn_s_setprio(0);

    float p[4][4];
    float pmax = -INFINITY;
#pragma unroll
    for (int t4 = 0; t4 < 4; ++t4)
#pragma unroll
      for (int r = 0; r < 4; ++r) p[t4][r] = st[t4][r];
    if (kt0 + 64 > ns) {  // tail tile: mask pad keys
#pragma unroll
      for (int t4 = 0; t4 < 4; ++t4)
#pragma unroll
        for (int r = 0; r < 4; ++r)
          if (kt0 + t4 * 16 + g * 4 + r >= ns) p[t4][r] = -1e9f;
    }
#pragma unroll
    for (int t4 = 0; t4 < 4; ++t4)
#pragma unroll
      for (int r = 0; r < 4; ++r) pmax = fmaxf(pmax, p[t4][r]);
    pmax = fmaxf(pmax, __shfl_xor(pmax, 16));
    pmax = fmaxf(pmax, __shfl_xor(pmax, 32));
    if (__any(pmax - m > 8.f)) {
      float mn = fmaxf(m, pmax);
      float sc = __expf(m - mn);
      m = mn;
      l *= sc;
#pragma unroll
      for (int dt = 0; dt < 6; ++dt)
#pragma unroll
        for (int r = 0; r < 4; ++r) o[dt][r] *= sc;
    }
    float ps = 0.f;
#pragma unroll
    for (int t4 = 0; t4 < 4; ++t4)
#pragma unroll
      for (int r = 0; r < 4; ++r) {
        float e = __expf(p[t4][r] - m);
        p[t4][r] = e;
        ps += e;
      }
    ps += __shfl_xor(ps, 16);
    ps += __shfl_xor(ps, 32);
    l += ps;

    // pack P -> bf16 B-fragments; slot e<4: k=32h2+4g+e, e>=4: k=32h2+16+4g+(e-4)
    short8 bp[2];
#pragma unroll
    for (int h2 = 0; h2 < 2; ++h2) {
      union { short8 s8; unsigned int u[4]; } u_;
      u_.u[0] = cvtpk(p[2 * h2][0], p[2 * h2][1]);
      u_.u[1] = cvtpk(p[2 * h2][2], p[2 * h2][3]);
      u_.u[2] = cvtpk(p[2 * h2 + 1][0], p[2 * h2 + 1][1]);
      u_.u[3] = cvtpk(p[2 * h2 + 1][2], p[2 * h2 + 1][3]);
      bp[h2] = u_.s8;
    }

    // PV: A = V^T with the same k-slot permutation
    __builtin_amdgcn_s_setprio(1);
#pragma unroll
    for (int dt = 0; dt < 6; ++dt)
#pragma unroll
      for (int h2 = 0; h2 < 2; ++h2) {
        union { short8 s8; short4 s4[2]; } a_;
        a_.s4[0] = *reinterpret_cast<const short4*>(&Vt[dt * 16 + lo][h2 * 32 + g * 4]);
        a_.s4[1] = *reinterpret_cast<const short4*>(&Vt[dt * 16 + lo][h2 * 32 + 16 + g * 4]);
        o[dt] = __builtin_amdgcn_mfma_f32_16x16x32_bf16(a_.s8, bp[h2], o[dt], 0, 0, 0);
      }
    __builtin_amdgcn_s_setprio(0);
    __syncthreads();
  }

  float inv = 1.f / l;
  size_t orow = ((size_t)(strm * M) + cb + bq0 + wave * 16 + lo) * C + h * HD;
#pragma unroll
  for (int dt = 0; dt < 6; ++dt)
#pragma unroll
    for (int r = 0; r < 4; ++r)
      Dc[orow + dt * 16 + g * 4 + r] = f2bf(o[dt][r] * inv);
}

// ---------------- final scatter with compaction indirection ----------------
__global__ __launch_bounds__(256) void final_kernel(const float* __restrict__ xc,
                                                    const int* __restrict__ sel,
                                                    const int* __restrict__ pos,
                                                    const int* __restrict__ coff,
                                                    const float* __restrict__ f_ir,
                                                    const float* __restrict__ f_vis,
                                                    float* __restrict__ out) {
  __shared__ float tile[32][33];
  int b = blockIdx.z;
  int s0 = blockIdx.x * 32, c0 = blockIdx.y * 32;
  int tx = threadIdx.x, ty = threadIdx.y;  // 32 x 8
  const int* selb = sel + b * S;
  const int* posb = pos + b * S;
  int cb = coff[b];
#pragma unroll
  for (int i = 0; i < 32; i += 8) {
    int s = s0 + ty + i;
    if (selb[s]) {
      size_t rc = cb + posb[s];
      tile[ty + i][tx] = xc[rc * C + c0 + tx] + xc[((size_t)M + rc) * C + c0 + tx];
    }
  }
  __syncthreads();
#pragma unroll
  for (int i = 0; i < 32; i += 8) {
    int c = c0 + ty + i, s = s0 + tx;
    size_t idx = ((size_t)(b * C + c)) * S + s;
    float v = selb[s] ? tile[tx][ty + i] : (f_ir[idx] + f_vis[idx]);
    out[idx] = v;
  }
}

}  // namespace

extern "C" void kernel_launch(void* const* d_in, const int* in_sizes, int n_in,
                              void* d_out, int out_size, void* d_ws, size_t ws_size,
                              hipStream_t stream) {
  const float* f_ir = (const float*)d_in[0];
  const float* f_vis = (const float*)d_in[1];
  const float* agent_w1 = (const float*)d_in[2];
  const float* agent_b1 = (const float*)d_in[3];
  const float* agent_w2 = (const float*)d_in[4];
  const float* agent_b2 = (const float*)d_in[5];
  const float* norm_g = (const float*)d_in[6];
  const float* norm_b = (const float*)d_in[7];
  const float* in_w = (const float*)d_in[8];
  const float* in_b = (const float*)d_in[9];
  const float* out_w = (const float*)d_in[10];
  const float* out_b = (const float*)d_in[11];
  const float* ffn_w1 = (const float*)d_in[12];
  const float* ffn_b1 = (const float*)d_in[13];
  const float* ffn_w2 = (const float*)d_in[14];
  const float* ffn_b2 = (const float*)d_in[15];
  float* out = (float*)d_out;

  constexpr size_t MS = (size_t)M * C;
  float* ws = (float*)d_ws;
  float* x0 = ws;                                  // fp32 [2M,C] full rows
  float* xc = x0 + 2 * MS;                         // fp32 [2M,C] compacted residual
  u16* Hc = (u16*)(xc + 2 * MS);                   // [2M,FFN] region (hosts aliases)
  u16* wb_in = Hc + (size_t)2 * M * FFN;           // 2*C3*C
  u16* wb_out = wb_in + 2 * C3 * C;                // 2*C*C
  u16* wb_f1 = wb_out + 2 * C * C;                 // 2*FFN*C
  u16* wb_f2 = wb_f1 + 2 * FFN * C;                // 2*C*FFN
  u16* w1b = wb_f2 + 2 * C * FFN;                  // HID*K2C
  int* sel = (int*)(w1b + HID * K2C);
  int* ctr = sel + M;
  int* fixlist = ctr + 1;
  int* pos = fixlist + FIXCAP;                     // [8][1024]
  int* nsel = pos + M;                             // [8]
  int* coff = nsel + 8;                            // [9]; coff[8] = Mcp
  float* part = (float*)(coff + 9);                // [FIXCAP*8] fixup partials
  // aliases inside Hc region (each dead before its successor is written):
  u16* Ahi = Hc;                                   // [M,768] agent act (dead after agent gemm)
  float* hiddenF = (float*)(Hc + (size_t)M * 768); // [M,HID] fp32 (dead after sel/fixup)
  u16* qkvc = Hc;                                  // [2M,C3] compacted QKV (dead before FFN1)
  u16* Dc = (u16*)x0;                              // [2M,C] bf16 (aliases x0 after gather)
  float* x1 = x0 + MS;

  // 0) all weights -> bf16 in one dispatch (also zeroes fixup ctr)
  cvt_all<<<(N4_ALL + 255) / 256, 256, 0, stream>>>(in_w, out_w, ffn_w1, ffn_w2,
                                                    agent_w1, wb_in, ctr);

  // 1) both transposes in one dispatch (fused agent bf16 activation emit)
  transpose_cs<<<dim3(S / 32, C / 32, 2 * B), dim3(32, 8), 0, stream>>>(
      f_ir, f_vis, x0, Ahi);

  // 2) agent hidden: single-pass bf16 MFMA + SiLU (fixup covers rounding)
  gemm_bf16<3><<<dim3(HID / 128, M / 128), 256, 0, stream>>>(
      Ahi, w1b, agent_b1, hiddenF, nullptr, HID, K2C, 0, 0, 0, 0, nullptr);

  // 3) selection mask + exact fp32 fixup (2-stage, parallel) + compaction meta
  sel_kernel<<<M, 64, 0, stream>>>(hiddenF, agent_w2, agent_b2, sel, ctr, fixlist);
  fixup_part<<<2048, 256, 0, stream>>>(x0, x1, agent_w1, agent_b1, agent_w2,
                                       ctr, fixlist, part);
  fixup_finish<<<FIXCAP / 64, 64, 0, stream>>>(part, agent_b2, ctr, fixlist, sel);
  prefix_kernel<<<B, 256, 0, stream>>>(sel, pos, nsel);
  boff_kernel<<<1, 64, 0, stream>>>(nsel, coff);

  // 4) gather selected rows -> compacted residual xc (pad rows zeroed)
  gather_x<<<2 * M, 64, 0, stream>>>(x0, sel, pos, coff, xc);
  zero_pad<<<16, 256, 0, stream>>>(nsel, coff, xc);

  // 5) compacted mixer, both streams z-batched (early-exit beyond coff[8])
  ln_kernel<<<2 * M, 64, 0, stream>>>(xc, norm_g, norm_b, Dc, coff);
  gemm_bf16<0><<<dim3(C3 / 128, M / 128, 2), 256, 0, stream>>>(
      Dc, wb_in, in_b, nullptr, qkvc, C3, C, M * C, C3 * C, C3, M * C3, coff + 8);
  attn_mfma<<<dim3(S / 64, B * HEADS * 2), 256, 0, stream>>>(qkvc, nsel, coff, Dc);
  gemm_bf16<2><<<dim3(C / 128, M / 128, 2), 256, 0, stream>>>(
      Dc, wb_out, out_b, xc, nullptr, C, C, M * C, C * C, C, M * C, coff + 8);
  ln_kernel<<<2 * M, 64, 0, stream>>>(xc, norm_g, norm_b, Dc, coff);
  gemm_bf16<1><<<dim3(FFN / 128, M / 128, 2), 256, 0, stream>>>(
      Dc, wb_f1, ffn_b1, nullptr, Hc, FFN, C, M * C, FFN * C, FFN, M * FFN, coff + 8);
  gemm_bf16<2><<<dim3(C / 128, M / 128, 2), 256, 0, stream>>>(
      Hc, wb_f2, ffn_b2, xc, nullptr, C, FFN, M * FFN, C * FFN, C, M * C, coff + 8);

  // 6) final scatter back to [B,C,H,W]
  final_kernel<<<dim3(S / 32, C / 32, B), dim3(32, 8), 0, stream>>>(
      xc, sel, pos, coff, f_ir, f_vis, out);
}

// Round 19
// 219.644 us; speedup vs baseline: 1.2803x; 1.1059x over previous
//
#include <hip/hip_runtime.h>
#include <math.h>

namespace {

constexpr int B = 8, C = 384, S = 1024;
constexpr int HID = 512, HEADS = 4, HD = 96, FFN = 1536;
constexpr int M = B * S;          // 8192 rows
constexpr int C3 = 3 * C;         // 1152
constexpr int K2C = 2 * C;        // 768 (agent K)
constexpr int FIXCAP = 4096;

using u16 = unsigned short;
using short8 = __attribute__((ext_vector_type(8))) short;
using short4 = __attribute__((ext_vector_type(4))) short;
using f32x4 = __attribute__((ext_vector_type(4))) float;
using u16x4 = __attribute__((ext_vector_type(4))) unsigned short;

__device__ inline u16 f2bf(float f) {
  unsigned int u = __builtin_bit_cast(unsigned int, f);
  u += 0x7fffu + ((u >> 16) & 1u);
  return (u16)(u >> 16);
}
__device__ inline float bf2f(u16 h) {
  unsigned int u = ((unsigned int)h) << 16;
  return __builtin_bit_cast(float, u);
}
__device__ inline unsigned int cvtpk(float a, float b) {  // [bf16(b)<<16 | bf16(a)]
  unsigned int r;
  asm("v_cvt_pk_bf16_f32 %0, %1, %2" : "=v"(r) : "v"(a), "v"(b));
  return r;
}

// ------- all weights -> bf16 in one dispatch; also zeroes fixup ctr ----
constexpr int N4_IN = 2 * C3 * C / 4;
constexpr int N4_OUT = 2 * C * C / 4;
constexpr int N4_F1 = 2 * FFN * C / 4;
constexpr int N4_F2 = 2 * C * FFN / 4;
constexpr int N4_W1 = HID * K2C / 4;
constexpr int N4_ALL = N4_IN + N4_OUT + N4_F1 + N4_F2 + N4_W1;

__global__ __launch_bounds__(256) void cvt_all(const float* __restrict__ in_w,
                                               const float* __restrict__ out_w,
                                               const float* __restrict__ f1,
                                               const float* __restrict__ f2,
                                               const float* __restrict__ w1,
                                               u16* __restrict__ dst,
                                               int* __restrict__ ctr) {
  int i = blockIdx.x * 256 + threadIdx.x;
  if (i == 0) ctr[0] = 0;
  if (i >= N4_ALL) return;
  const float* src;
  int off = i;
  if (i < N4_IN) {
    src = in_w;
  } else if (i < N4_IN + N4_OUT) {
    src = out_w; off = i - N4_IN;
  } else if (i < N4_IN + N4_OUT + N4_F1) {
    src = f1; off = i - N4_IN - N4_OUT;
  } else if (i < N4_IN + N4_OUT + N4_F1 + N4_F2) {
    src = f2; off = i - N4_IN - N4_OUT - N4_F1;
  } else {
    src = w1; off = i - N4_IN - N4_OUT - N4_F1 - N4_F2;
  }
  f32x4 v = reinterpret_cast<const f32x4*>(src)[off];
  u16x4 o;
#pragma unroll
  for (int j = 0; j < 4; ++j) o[j] = f2bf(v[j]);
  reinterpret_cast<u16x4*>(dst)[i] = o;
}

// ------- both transposes [C,S]->[S,C] in one dispatch, fused agent bf16 emit --
__global__ __launch_bounds__(256) void transpose_cs(const float* __restrict__ f_ir,
                                                    const float* __restrict__ f_vis,
                                                    float* __restrict__ x0,
                                                    u16* __restrict__ Ahi) {
  __shared__ float tile[32][33];
  int bz = blockIdx.z;
  int b = bz & 7, which = bz >> 3;
  const float* in = which ? f_vis : f_ir;
  float* out = x0 + (size_t)which * M * C;
  int coff = which ? C : 0;
  int s0 = blockIdx.x * 32, c0 = blockIdx.y * 32;
  const float* ip = in + (size_t)b * C * S;
  float* op = out + (size_t)b * S * C;
  int tx = threadIdx.x, ty = threadIdx.y;   // 32 x 8
#pragma unroll
  for (int i = 0; i < 32; i += 8)
    tile[ty + i][tx] = ip[(size_t)(c0 + ty + i) * S + s0 + tx];
  __syncthreads();
#pragma unroll
  for (int i = 0; i < 32; i += 8) {
    int s = s0 + ty + i;
    float v = tile[tx][ty + i];
    op[(size_t)s * C + c0 + tx] = v;
    Ahi[(size_t)(b * S + s) * K2C + coff + c0 + tx] = f2bf(v);
  }
}

// ---------------- bf16 MFMA GEMM helpers (swizzled global_load_lds) ----------
template <int TROWS>
__device__ inline void stage_tile(const u16* __restrict__ g, int ldk,
                                  u16* lds, int tid) {
  int w = tid >> 6, l = tid & 63;
#pragma unroll
  for (int i = 0; i < TROWS / 32; ++i) {
    int lin = i * 4096 + w * 1024 + l * 16;   // byte within tile
    int row = lin >> 7;                        // 128B per row (64 bf16)
    int slot = (lin >> 4) & 7;
    int k = (slot ^ (row & 7)) * 8;            // inverse-swizzled source
    const u16* gp = g + (size_t)row * ldk + k;
    u16* lp = lds + i * 2048 + w * 512;        // wave-uniform dest (elements)
    __builtin_amdgcn_global_load_lds(
        (const __attribute__((address_space(1))) unsigned int*)gp,
        (__attribute__((address_space(3))) unsigned int*)lp, 16, 0, 0);
  }
}

__device__ inline short8 frag_ld(const u16* lds, int row, int slot) {
  int s = slot ^ (row & 7);
  return *reinterpret_cast<const short8*>(lds + row * 64 + s * 8);
}

// out[M,N] = A[M,K](bf16) * W[N,K]^T(bf16); BMx128 tile, BK=64, 4 waves 2x2
// (wave tile BM/2 x 64). MODE 0: +bias -> bf16. 1: +bias,GELU -> bf16.
// 2: +bias += fp32 xres. 3: +bias,SiLU -> fp32 xres.
// mbound (nullable): device row bound; blocks with bm >= *mbound exit.
template <int MODE, int BM>
__global__ __launch_bounds__(256) void gemm_bf16(const u16* __restrict__ A,
                                                 const u16* __restrict__ W,
                                                 const float* __restrict__ bias,
                                                 float* __restrict__ xres,
                                                 u16* __restrict__ obf,
                                                 int N, int K,
                                                 int zsA, int zsW, int zsB, int zsO,
                                                 const int* __restrict__ mbound) {
  __shared__ u16 Asb[BM * 64];
  __shared__ u16 Wsb[128 * 64];
  constexpr int MI = BM / 32;                // M-frags per wave
  int bn = blockIdx.x * 128, bm = blockIdx.y * BM;
  if (mbound && bm >= *mbound) return;
  int z = blockIdx.z;
  if (z) {
    A += (size_t)z * zsA;
    W += (size_t)z * zsW;
    bias += (size_t)z * zsB;
    if (MODE == 2 || MODE == 3) xres += (size_t)z * zsO;
    else obf += (size_t)z * zsO;
  }
  int tid = threadIdx.x;
  int wave = tid >> 6, lane = tid & 63, lo = lane & 15, hi = lane >> 4;
  int wr = wave >> 1, wc = wave & 1;
  const u16* Ag = A + (size_t)bm * K;
  const u16* Wg = W + (size_t)bn * K;
  f32x4 acc[MI][4] = {};
  for (int k0 = 0; k0 < K; k0 += 64) {
    stage_tile<BM>(Ag + k0, K, Asb, tid);
    stage_tile<128>(Wg + k0, K, Wsb, tid);
    __syncthreads();
#pragma unroll
    for (int ks = 0; ks < 2; ++ks) {
      short8 a[MI], b[4];
#pragma unroll
      for (int mi = 0; mi < MI; ++mi)
        a[mi] = frag_ld(Asb, wr * (BM / 2) + mi * 16 + lo, ks * 4 + hi);
#pragma unroll
      for (int nj = 0; nj < 4; ++nj)
        b[nj] = frag_ld(Wsb, wc * 64 + nj * 16 + lo, ks * 4 + hi);
#pragma unroll
      for (int mi = 0; mi < MI; ++mi)
#pragma unroll
        for (int nj = 0; nj < 4; ++nj)
          acc[mi][nj] = __builtin_amdgcn_mfma_f32_16x16x32_bf16(a[mi], b[nj], acc[mi][nj], 0, 0, 0);
    }
    __syncthreads();
  }
  float bv[4];
#pragma unroll
  for (int nj = 0; nj < 4; ++nj) bv[nj] = bias[bn + wc * 64 + nj * 16 + lo];
#pragma unroll
  for (int mi = 0; mi < MI; ++mi) {
#pragma unroll
    for (int r = 0; r < 4; ++r) {
      int m = bm + wr * (BM / 2) + mi * 16 + hi * 4 + r;
#pragma unroll
      for (int nj = 0; nj < 4; ++nj) {
        int n = bn + wc * 64 + nj * 16 + lo;
        float v = acc[mi][nj][r] + bv[nj];
        size_t idx = (size_t)m * N + n;
        if (MODE == 0) {
          obf[idx] = f2bf(v);
        } else if (MODE == 1) {
          v = 0.5f * v * (1.f + erff(v * 0.70710678f));
          obf[idx] = f2bf(v);
        } else if (MODE == 2) {
          xres[idx] += v;
        } else {  // MODE 3
          xres[idx] = v / (1.f + expf(-v));
        }
      }
    }
  }
}

// ---------------- agent logit + threshold + ambiguity list ----------------
// Threshold 0.02: single-pass bf16 logit error rms ~1.4e-3 -> 14-sigma margin;
// all |logit| < 0.02 rows recomputed exactly in fp32 by fixup_part/finish.
__global__ __launch_bounds__(64) void sel_kernel(const float* __restrict__ hidden,
                                                 const float* __restrict__ w2,
                                                 const float* __restrict__ b2,
                                                 int* __restrict__ sel,
                                                 int* __restrict__ ctr,
                                                 int* __restrict__ list) {
  int row = blockIdx.x, t = threadIdx.x;
  const float* hr = hidden + (size_t)row * HID;
  float s = 0.f;
#pragma unroll
  for (int i = 0; i < HID / 64; ++i) s += hr[t + i * 64] * w2[t + i * 64];
  for (int off = 32; off; off >>= 1) s += __shfl_down(s, off);
  if (t == 0) {
    float logit = s + b2[0];
    sel[row] = logit > 0.f ? 1 : 0;
    if (fabsf(logit) < 0.02f) {
      int idx = atomicAdd(ctr, 1);
      if (idx < FIXCAP) list[idx] = row;
    }
  }
}

// ------- fixup stage 1: per-(flagged row, 64-unit chunk) partial logit -------
__global__ __launch_bounds__(256) void fixup_part(const float* __restrict__ x0,
                                                  const float* __restrict__ x1,
                                                  const float* __restrict__ w1,
                                                  const float* __restrict__ b1,
                                                  const float* __restrict__ w2,
                                                  const int* __restrict__ ctr,
                                                  const int* __restrict__ list,
                                                  float* __restrict__ part) {
  __shared__ float xs[K2C];
  __shared__ float red[4];
  int cnt = ctr[0];
  if (cnt > FIXCAP) cnt = FIXCAP;
  int items = cnt * 8;
  int tid = threadIdx.x;
  f32x4* xsv = reinterpret_cast<f32x4*>(xs);
  for (int w = blockIdx.x; w < items; w += gridDim.x) {
    int ii = w >> 3, chunk = w & 7;
    int row = list[ii];
    if (tid < 96) xsv[tid] = reinterpret_cast<const f32x4*>(x0 + (size_t)row * C)[tid];
    else if (tid < 192)
      xsv[tid] = reinterpret_cast<const f32x4*>(x1 + (size_t)row * C)[tid - 96];
    __syncthreads();
    int n = chunk * 64 + (tid >> 2);   // hidden unit
    int q = tid & 3;                    // K quarter
    const f32x4* wr = reinterpret_cast<const f32x4*>(w1 + (size_t)n * K2C) + q * 48;
    const f32x4* xq = xsv + q * 48;
    float a0 = 0.f, a1 = 0.f, a2 = 0.f, a3 = 0.f;
#pragma unroll 12
    for (int k = 0; k < 48; ++k) {
      f32x4 wv = wr[k], xv = xq[k];
      a0 = fmaf(wv[0], xv[0], a0);
      a1 = fmaf(wv[1], xv[1], a1);
      a2 = fmaf(wv[2], xv[2], a2);
      a3 = fmaf(wv[3], xv[3], a3);
    }
    float d = (a0 + a1) + (a2 + a3);
    d += __shfl_xor(d, 1);
    d += __shfl_xor(d, 2);
    float pl = 0.f;
    if (q == 0) {
      float acc = d + b1[n];
      acc = acc / (1.f + expf(-acc));  // SiLU
      pl = acc * w2[n];
    }
    for (int off = 32; off; off >>= 1) pl += __shfl_down(pl, off);
    if ((tid & 63) == 0) red[tid >> 6] = pl;
    __syncthreads();
    if (tid == 0) part[w] = red[0] + red[1] + red[2] + red[3];
    __syncthreads();
  }
}

// ------- fixup stage 2: deterministic 8-way sum + sign decision -------
__global__ __launch_bounds__(64) void fixup_finish(const float* __restrict__ part,
                                                   const float* __restrict__ b2,
                                                   const int* __restrict__ ctr,
                                                   const int* __restrict__ list,
                                                   int* __restrict__ sel) {
  int ii = blockIdx.x * 64 + threadIdx.x;
  int cnt = ctr[0];
  if (cnt > FIXCAP) cnt = FIXCAP;
  if (ii >= cnt) return;
  float s = b2[0];
#pragma unroll
  for (int j = 0; j < 8; ++j) s += part[ii * 8 + j];
  sel[list[ii]] = s > 0.f ? 1 : 0;
}

// ---------------- per-batch exclusive prefix scan of sel ----------------
__global__ __launch_bounds__(256) void prefix_kernel(const int* __restrict__ sel,
                                                     int* __restrict__ pos,
                                                     int* __restrict__ nsel) {
  __shared__ int wsum[4];
  int b = blockIdx.x, tid = threadIdx.x;
  int lane = tid & 63, wv = tid >> 6;
  int v[4], lp[4];
  int tot = 0;
#pragma unroll
  for (int j = 0; j < 4; ++j) {
    v[j] = sel[b * S + tid * 4 + j];
    lp[j] = tot;
    tot += v[j];
  }
  int inc = tot;
#pragma unroll
  for (int off = 1; off < 64; off <<= 1) {
    int n = __shfl_up(inc, off);
    if (lane >= off) inc += n;
  }
  if (lane == 63) wsum[wv] = inc;
  __syncthreads();
  int wbase = 0;
#pragma unroll
  for (int w = 0; w < 4; ++w)
    if (w < wv) wbase += wsum[w];
  int ex = wbase + inc - tot;
#pragma unroll
  for (int j = 0; j < 4; ++j) pos[b * S + tid * 4 + j] = ex + lp[j];
  if (tid == 0) nsel[b] = wsum[0] + wsum[1] + wsum[2] + wsum[3];
}

// ---------------- per-batch 64-aligned compacted offsets ----------------
__global__ void boff_kernel(const int* __restrict__ nsel, int* __restrict__ coff) {
  if (threadIdx.x == 0) {
    int acc = 0;
    for (int b = 0; b < 8; ++b) {
      coff[b] = acc;
      acc += (nsel[b] + 63) & ~63;
    }
    coff[8] = acc;  // Mcp (64-aligned total compacted rows per stream)
  }
}

// ------- gather selected x rows into compacted xc (+ fused pad zeroing) ------
// Blocks [0, 2M): gather. Blocks [2M, 2M+16): zero per-(stream,batch) pad rows.
__global__ __launch_bounds__(64) void gather_x(const float* __restrict__ x0,
                                               const int* __restrict__ sel,
                                               const int* __restrict__ pos,
                                               const int* __restrict__ coff,
                                               const int* __restrict__ nsel,
                                               float* __restrict__ xc) {
  int bid = blockIdx.x;
  if (bid >= 2 * M) {
    int z = bid - 2 * M;                // 16 = 2 streams x 8 batches
    int strm = z >> 3, b = z & 7;
    int ns = nsel[b];
    int npad = ((ns + 63) & ~63) - ns;
    f32x4* base = reinterpret_cast<f32x4*>(
        xc + ((size_t)(strm * M) + coff[b] + ns) * C);
    int tot = npad * (C / 4);
    f32x4 zz = {};
    for (int i = threadIdx.x; i < tot; i += 64) base[i] = zz;
    return;
  }
  int row = bid;                        // 0..2M
  int bs = row & (M - 1);
  if (!sel[bs]) return;
  int strm = row >> 13, b = bs >> 10;
  int rc = coff[b] + pos[bs];
  const f32x4* src = reinterpret_cast<const f32x4*>(x0 + (size_t)row * C);
  f32x4* dst = reinterpret_cast<f32x4*>(xc + ((size_t)(strm * M) + rc) * C);
  int t = threadIdx.x;
  dst[t] = src[t];
  if (t < 32) dst[t + 64] = src[t + 64];
}

// ---------------- compacted LayerNorm -> bf16, one wave per row ----------------
__global__ __launch_bounds__(64) void ln_kernel(const float* __restrict__ x,
                                                const float* __restrict__ g_all,
                                                const float* __restrict__ b_all,
                                                u16* __restrict__ y,
                                                const int* __restrict__ coff) {
  int row = blockIdx.x, t = threadIdx.x;
  int strm = row >> 13, rc = row & (M - 1);
  if (rc >= coff[8]) return;
  const float* g = g_all + strm * C;
  const float* bt = b_all + strm * C;
  const float* xr = x + (size_t)row * C;
  float v[C / 64];
  float s = 0.f, s2 = 0.f;
#pragma unroll
  for (int i = 0; i < C / 64; ++i) {
    float a = xr[t + i * 64];
    v[i] = a;
    s += a;
    s2 += a * a;
  }
  for (int off = 32; off; off >>= 1) {
    s += __shfl_down(s, off);
    s2 += __shfl_down(s2, off);
  }
  s = __shfl(s, 0);
  s2 = __shfl(s2, 0);
  float mean = s / C;
  float var = s2 / C - mean * mean;
  float inv = rsqrtf(var + 1e-5f);
#pragma unroll
  for (int i = 0; i < C / 64; ++i) {
    int c = t + i * 64;
    y[(size_t)row * C + c] = f2bf((v[i] - mean) * inv * g[c] + bt[c]);
  }
}

// ---------------- flash MFMA attention v6 (fully compacted rows) --------------
__global__ __launch_bounds__(256) void attn_mfma(const u16* __restrict__ qkvc,
                                                 const int* __restrict__ nsel,
                                                 const int* __restrict__ coff,
                                                 u16* __restrict__ Dc) {
  __shared__ u16 Ks[64][104];
  __shared__ u16 Vt[96][72];

  int bq0 = blockIdx.x * 64;
  int bh2 = blockIdx.y;                  // 64 = 2 streams x 8 b x 4 h
  int strm = bh2 >> 5, bh = bh2 & 31;
  int b = bh >> 2, h = bh & 3;
  int ns = nsel[b];
  if (bq0 >= ns) return;
  int cb = coff[b];
  const u16* qbase = qkvc + ((size_t)(strm * M) + cb) * C3;
  int tid = threadIdx.x;
  int wave = tid >> 6, lane = tid & 63;
  int lo = lane & 15, g = lane >> 4;

  // Q fragments in registers, pre-scaled by 1/sqrt(HD)
  const float scale = 0.1020620726f;
  short8 bq[3];
  const u16* qrow = qbase + (size_t)(bq0 + wave * 16 + lo) * C3 + h * HD;
#pragma unroll
  for (int c = 0; c < 3; ++c) {
    short8 q = *reinterpret_cast<const short8*>(qrow + c * 32 + g * 8);
    short8 r;
#pragma unroll
    for (int e = 0; e < 8; ++e) r[e] = (short)f2bf(bf2f((u16)q[e]) * scale);
    bq[c] = r;
  }

  float m = -30.f, l = 0.f;
  f32x4 o[6] = {};
  int nt64 = (ns + 63) & ~63;

  for (int kt0 = 0; kt0 < nt64; kt0 += 64) {
    const u16* kbase = qbase + (size_t)kt0 * C3 + C + h * HD;
    const u16* vbase = qbase + (size_t)kt0 * C3 + 2 * C + h * HD;
#pragma unroll
    for (int i = 0; i < 3; ++i) {
      int idx = i * 256 + tid;
      int r = idx / 12, j = idx - r * 12;
      *reinterpret_cast<short8*>(&Ks[r][j * 8]) =
          *reinterpret_cast<const short8*>(kbase + (size_t)r * C3 + j * 8);
    }
#pragma unroll
    for (int i = 0; i < 3; ++i) {
      int idx = i * 256 + tid;
      int r = idx & 63, j = idx >> 6;
      short8 v = *reinterpret_cast<const short8*>(vbase + (size_t)r * C3 + j * 8);
#pragma unroll
      for (int e = 0; e < 8; ++e) Vt[j * 8 + e][r] = (u16)v[e];
    }
    __syncthreads();

    // QK^T: st[t4][r] = S[k=kt0+16t4+4g+r][q=lo]
    f32x4 st[4] = {};
    __builtin_amdgcn_s_setprio(1);
#pragma unroll
    for (int c = 0; c < 3; ++c)
#pragma unroll
      for (int t4 = 0; t4 < 4; ++t4) {
        short8 ak = *reinterpret_cast<const short8*>(&Ks[t4 * 16 + lo][c * 32 + g * 8]);
        st[t4] = __builtin_amdgcn_mfma_f32_16x16x32_bf16(ak, bq[c], st[t4], 0, 0, 0);
      }
    __builtin_amdgcn_s_setprio(0);

    float p[4][4];
    float pmax = -INFINITY;
#pragma unroll
    for (int t4 = 0; t4 < 4; ++t4)
#pragma unroll
      for (int r = 0; r < 4; ++r) p[t4][r] = st[t4][r];
    if (kt0 + 64 > ns) {  // tail tile: mask pad keys
#pragma unroll
      for (int t4 = 0; t4 < 4; ++t4)
#pragma unroll
        for (int r = 0; r < 4; ++r)
          if (kt0 + t4 * 16 + g * 4 + r >= ns) p[t4][r] = -1e9f;
    }
#pragma unroll
    for (int t4 = 0; t4 < 4; ++t4)
#pragma unroll
      for (int r = 0; r < 4; ++r) pmax = fmaxf(pmax, p[t4][r]);
    pmax = fmaxf(pmax, __shfl_xor(pmax, 16));
    pmax = fmaxf(pmax, __shfl_xor(pmax, 32));
    if (__any(pmax - m > 8.f)) {
      float mn = fmaxf(m, pmax);
      float sc = __expf(m - mn);
      m = mn;
      l *= sc;
#pragma unroll
      for (int dt = 0; dt < 6; ++dt)
#pragma unroll
        for (int r = 0; r < 4; ++r) o[dt][r] *= sc;
    }
    float ps = 0.f;
#pragma unroll
    for (int t4 = 0; t4 < 4; ++t4)
#pragma unroll
      for (int r = 0; r < 4; ++r) {
        float e = __expf(p[t4][r] - m);
        p[t4][r] = e;
        ps += e;
      }
    ps += __shfl_xor(ps, 16);
    ps += __shfl_xor(ps, 32);
    l += ps;

    // pack P -> bf16 B-fragments; slot e<4: k=32h2+4g+e, e>=4: k=32h2+16+4g+(e-4)
    short8 bp[2];
#pragma unroll
    for (int h2 = 0; h2 < 2; ++h2) {
      union { short8 s8; unsigned int u[4]; } u_;
      u_.u[0] = cvtpk(p[2 * h2][0], p[2 * h2][1]);
      u_.u[1] = cvtpk(p[2 * h2][2], p[2 * h2][3]);
      u_.u[2] = cvtpk(p[2 * h2 + 1][0], p[2 * h2 + 1][1]);
      u_.u[3] = cvtpk(p[2 * h2 + 1][2], p[2 * h2 + 1][3]);
      bp[h2] = u_.s8;
    }

    // PV: A = V^T with the same k-slot permutation
    __builtin_amdgcn_s_setprio(1);
#pragma unroll
    for (int dt = 0; dt < 6; ++dt)
#pragma unroll
      for (int h2 = 0; h2 < 2; ++h2) {
        union { short8 s8; short4 s4[2]; } a_;
        a_.s4[0] = *reinterpret_cast<const short4*>(&Vt[dt * 16 + lo][h2 * 32 + g * 4]);
        a_.s4[1] = *reinterpret_cast<const short4*>(&Vt[dt * 16 + lo][h2 * 32 + 16 + g * 4]);
        o[dt] = __builtin_amdgcn_mfma_f32_16x16x32_bf16(a_.s8, bp[h2], o[dt], 0, 0, 0);
      }
    __builtin_amdgcn_s_setprio(0);
    __syncthreads();
  }

  float inv = 1.f / l;
  size_t orow = ((size_t)(strm * M) + cb + bq0 + wave * 16 + lo) * C + h * HD;
#pragma unroll
  for (int dt = 0; dt < 6; ++dt)
#pragma unroll
    for (int r = 0; r < 4; ++r)
      Dc[orow + dt * 16 + g * 4 + r] = f2bf(o[dt][r] * inv);
}

// ---------------- final scatter with compaction indirection ----------------
__global__ __launch_bounds__(256) void final_kernel(const float* __restrict__ xc,
                                                    const int* __restrict__ sel,
                                                    const int* __restrict__ pos,
                                                    const int* __restrict__ coff,
                                                    const float* __restrict__ f_ir,
                                                    const float* __restrict__ f_vis,
                                                    float* __restrict__ out) {
  __shared__ float tile[32][33];
  int b = blockIdx.z;
  int s0 = blockIdx.x * 32, c0 = blockIdx.y * 32;
  int tx = threadIdx.x, ty = threadIdx.y;  // 32 x 8
  const int* selb = sel + b * S;
  const int* posb = pos + b * S;
  int cb = coff[b];
#pragma unroll
  for (int i = 0; i < 32; i += 8) {
    int s = s0 + ty + i;
    if (selb[s]) {
      size_t rc = cb + posb[s];
      tile[ty + i][tx] = xc[rc * C + c0 + tx] + xc[((size_t)M + rc) * C + c0 + tx];
    }
  }
  __syncthreads();
#pragma unroll
  for (int i = 0; i < 32; i += 8) {
    int c = c0 + ty + i, s = s0 + tx;
    size_t idx = ((size_t)(b * C + c)) * S + s;
    float v = selb[s] ? tile[tx][ty + i] : (f_ir[idx] + f_vis[idx]);
    out[idx] = v;
  }
}

}  // namespace

extern "C" void kernel_launch(void* const* d_in, const int* in_sizes, int n_in,
                              void* d_out, int out_size, void* d_ws, size_t ws_size,
                              hipStream_t stream) {
  const float* f_ir = (const float*)d_in[0];
  const float* f_vis = (const float*)d_in[1];
  const float* agent_w1 = (const float*)d_in[2];
  const float* agent_b1 = (const float*)d_in[3];
  const float* agent_w2 = (const float*)d_in[4];
  const float* agent_b2 = (const float*)d_in[5];
  const float* norm_g = (const float*)d_in[6];
  const float* norm_b = (const float*)d_in[7];
  const float* in_w = (const float*)d_in[8];
  const float* in_b = (const float*)d_in[9];
  const float* out_w = (const float*)d_in[10];
  const float* out_b = (const float*)d_in[11];
  const float* ffn_w1 = (const float*)d_in[12];
  const float* ffn_b1 = (const float*)d_in[13];
  const float* ffn_w2 = (const float*)d_in[14];
  const float* ffn_b2 = (const float*)d_in[15];
  float* out = (float*)d_out;

  constexpr size_t MS = (size_t)M * C;
  float* ws = (float*)d_ws;
  float* x0 = ws;                                  // fp32 [2M,C] full rows
  float* xc = x0 + 2 * MS;                         // fp32 [2M,C] compacted residual
  u16* Hc = (u16*)(xc + 2 * MS);                   // [2M,FFN] region (hosts aliases)
  u16* wb_in = Hc + (size_t)2 * M * FFN;           // 2*C3*C
  u16* wb_out = wb_in + 2 * C3 * C;                // 2*C*C
  u16* wb_f1 = wb_out + 2 * C * C;                 // 2*FFN*C
  u16* wb_f2 = wb_f1 + 2 * FFN * C;                // 2*C*FFN
  u16* w1b = wb_f2 + 2 * C * FFN;                  // HID*K2C
  int* sel = (int*)(w1b + HID * K2C);
  int* ctr = sel + M;
  int* fixlist = ctr + 1;
  int* pos = fixlist + FIXCAP;                     // [8][1024]
  int* nsel = pos + M;                             // [8]
  int* coff = nsel + 8;                            // [9]; coff[8] = Mcp
  float* part = (float*)(coff + 9);                // [FIXCAP*8] fixup partials
  // aliases inside Hc region (each dead before its successor is written):
  u16* Ahi = Hc;                                   // [M,768] agent act (dead after agent gemm)
  float* hiddenF = (float*)(Hc + (size_t)M * 768); // [M,HID] fp32 (dead after sel/fixup)
  u16* qkvc = Hc;                                  // [2M,C3] compacted QKV (dead before FFN1)
  u16* Dc = (u16*)x0;                              // [2M,C] bf16 (aliases x0 after gather)
  float* x1 = x0 + MS;

  // 0) all weights -> bf16 in one dispatch (also zeroes fixup ctr)
  cvt_all<<<(N4_ALL + 255) / 256, 256, 0, stream>>>(in_w, out_w, ffn_w1, ffn_w2,
                                                    agent_w1, wb_in, ctr);

  // 1) both transposes in one dispatch (fused agent bf16 activation emit)
  transpose_cs<<<dim3(S / 32, C / 32, 2 * B), dim3(32, 8), 0, stream>>>(
      f_ir, f_vis, x0, Ahi);

  // 2) agent hidden: single-pass bf16 MFMA + SiLU, BM=64 (2 blocks/CU)
  gemm_bf16<3, 64><<<dim3(HID / 128, M / 64), 256, 0, stream>>>(
      Ahi, w1b, agent_b1, hiddenF, nullptr, HID, K2C, 0, 0, 0, 0, nullptr);

  // 3) selection mask + exact fp32 fixup (2-stage, parallel) + compaction meta
  sel_kernel<<<M, 64, 0, stream>>>(hiddenF, agent_w2, agent_b2, sel, ctr, fixlist);
  fixup_part<<<2048, 256, 0, stream>>>(x0, x1, agent_w1, agent_b1, agent_w2,
                                       ctr, fixlist, part);
  fixup_finish<<<FIXCAP / 64, 64, 0, stream>>>(part, agent_b2, ctr, fixlist, sel);
  prefix_kernel<<<B, 256, 0, stream>>>(sel, pos, nsel);
  boff_kernel<<<1, 64, 0, stream>>>(nsel, coff);

  // 4) gather selected rows -> compacted residual xc (pad zeroing fused)
  gather_x<<<2 * M + 16, 64, 0, stream>>>(x0, sel, pos, coff, nsel, xc);

  // 5) compacted mixer, both streams z-batched (early-exit beyond coff[8])
  ln_kernel<<<2 * M, 64, 0, stream>>>(xc, norm_g, norm_b, Dc, coff);
  gemm_bf16<0, 128><<<dim3(C3 / 128, M / 128, 2), 256, 0, stream>>>(
      Dc, wb_in, in_b, nullptr, qkvc, C3, C, M * C, C3 * C, C3, M * C3, coff + 8);
  attn_mfma<<<dim3(S / 64, B * HEADS * 2), 256, 0, stream>>>(qkvc, nsel, coff, Dc);
  gemm_bf16<2, 64><<<dim3(C / 128, M / 64, 2), 256, 0, stream>>>(
      Dc, wb_out, out_b, xc, nullptr, C, C, M * C, C * C, C, M * C, coff + 8);
  ln_kernel<<<2 * M, 64, 0, stream>>>(xc, norm_g, norm_b, Dc, coff);
  gemm_bf16<1, 128><<<dim3(FFN / 128, M / 128, 2), 256, 0, stream>>>(
      Dc, wb_f1, ffn_b1, nullptr, Hc, FFN, C, M * C, FFN * C, FFN, M * FFN, coff + 8);
  gemm_bf16<2, 64><<<dim3(C / 128, M / 64, 2), 256, 0, stream>>>(
      Hc, wb_f2, ffn_b2, xc, nullptr, C, FFN, M * FFN, C * FFN, C, M * C, coff + 8);

  // 6) final scatter back to [B,C,H,W]
  final_kernel<<<dim3(S / 32, C / 32, B), dim3(32, 8), 0, stream>>>(
      xc, sel, pos, coff, f_ir, f_vis, out);
}

// Round 22
// 215.053 us; speedup vs baseline: 1.3076x; 1.0213x over previous
//
#include <hip/hip_runtime.h>
#include <math.h>

namespace {

constexpr int B = 8, C = 384, S = 1024;
constexpr int HID = 512, HEADS = 4, HD = 96, FFN = 1536;
constexpr int M = B * S;          // 8192 rows
constexpr int C3 = 3 * C;         // 1152
constexpr int K2C = 2 * C;        // 768 (agent K)
constexpr int FIXCAP = 4096;

using u16 = unsigned short;
using short8 = __attribute__((ext_vector_type(8))) short;
using short4 = __attribute__((ext_vector_type(4))) short;
using f32x4 = __attribute__((ext_vector_type(4))) float;
using u16x4 = __attribute__((ext_vector_type(4))) unsigned short;

__device__ inline u16 f2bf(float f) {
  unsigned int u = __builtin_bit_cast(unsigned int, f);
  u += 0x7fffu + ((u >> 16) & 1u);
  return (u16)(u >> 16);
}
__device__ inline float bf2f(u16 h) {
  unsigned int u = ((unsigned int)h) << 16;
  return __builtin_bit_cast(float, u);
}
__device__ inline unsigned int cvtpk(float a, float b) {  // [bf16(b)<<16 | bf16(a)]
  unsigned int r;
  asm("v_cvt_pk_bf16_f32 %0, %1, %2" : "=v"(r) : "v"(a), "v"(b));
  return r;
}

// ------- all weights -> bf16 in one dispatch; also zeroes fixup ctr ----
constexpr int N4_IN = 2 * C3 * C / 4;
constexpr int N4_OUT = 2 * C * C / 4;
constexpr int N4_F1 = 2 * FFN * C / 4;
constexpr int N4_F2 = 2 * C * FFN / 4;
constexpr int N4_W1 = HID * K2C / 4;
constexpr int N4_ALL = N4_IN + N4_OUT + N4_F1 + N4_F2 + N4_W1;

__global__ __launch_bounds__(256) void cvt_all(const float* __restrict__ in_w,
                                               const float* __restrict__ out_w,
                                               const float* __restrict__ f1,
                                               const float* __restrict__ f2,
                                               const float* __restrict__ w1,
                                               u16* __restrict__ dst,
                                               int* __restrict__ ctr) {
  int i = blockIdx.x * 256 + threadIdx.x;
  if (i == 0) ctr[0] = 0;
  if (i >= N4_ALL) return;
  const float* src;
  int off = i;
  if (i < N4_IN) {
    src = in_w;
  } else if (i < N4_IN + N4_OUT) {
    src = out_w; off = i - N4_IN;
  } else if (i < N4_IN + N4_OUT + N4_F1) {
    src = f1; off = i - N4_IN - N4_OUT;
  } else if (i < N4_IN + N4_OUT + N4_F1 + N4_F2) {
    src = f2; off = i - N4_IN - N4_OUT - N4_F1;
  } else {
    src = w1; off = i - N4_IN - N4_OUT - N4_F1 - N4_F2;
  }
  f32x4 v = reinterpret_cast<const f32x4*>(src)[off];
  u16x4 o;
#pragma unroll
  for (int j = 0; j < 4; ++j) o[j] = f2bf(v[j]);
  reinterpret_cast<u16x4*>(dst)[i] = o;
}

// ------- both transposes [C,S]->[S,C] in one dispatch, fused agent bf16 emit --
__global__ __launch_bounds__(256) void transpose_cs(const float* __restrict__ f_ir,
                                                    const float* __restrict__ f_vis,
                                                    float* __restrict__ x0,
                                                    u16* __restrict__ Ahi) {
  __shared__ float tile[32][33];
  int bz = blockIdx.z;
  int b = bz & 7, which = bz >> 3;
  const float* in = which ? f_vis : f_ir;
  float* out = x0 + (size_t)which * M * C;
  int coff = which ? C : 0;
  int s0 = blockIdx.x * 32, c0 = blockIdx.y * 32;
  const float* ip = in + (size_t)b * C * S;
  float* op = out + (size_t)b * S * C;
  int tx = threadIdx.x, ty = threadIdx.y;   // 32 x 8
#pragma unroll
  for (int i = 0; i < 32; i += 8)
    tile[ty + i][tx] = ip[(size_t)(c0 + ty + i) * S + s0 + tx];
  __syncthreads();
#pragma unroll
  for (int i = 0; i < 32; i += 8) {
    int s = s0 + ty + i;
    float v = tile[tx][ty + i];
    op[(size_t)s * C + c0 + tx] = v;
    Ahi[(size_t)(b * S + s) * K2C + coff + c0 + tx] = f2bf(v);
  }
}

// ---------------- bf16 MFMA GEMM helpers (swizzled global_load_lds) ----------
template <int TROWS>
__device__ inline void stage_tile(const u16* __restrict__ g, int ldk,
                                  u16* lds, int tid) {
  int w = tid >> 6, l = tid & 63;
#pragma unroll
  for (int i = 0; i < TROWS / 32; ++i) {
    int lin = i * 4096 + w * 1024 + l * 16;   // byte within tile
    int row = lin >> 7;                        // 128B per row (64 bf16)
    int slot = (lin >> 4) & 7;
    int k = (slot ^ (row & 7)) * 8;            // inverse-swizzled source
    const u16* gp = g + (size_t)row * ldk + k;
    u16* lp = lds + i * 2048 + w * 512;        // wave-uniform dest (elements)
    __builtin_amdgcn_global_load_lds(
        (const __attribute__((address_space(1))) unsigned int*)gp,
        (__attribute__((address_space(3))) unsigned int*)lp, 16, 0, 0);
  }
}

__device__ inline short8 frag_ld(const u16* lds, int row, int slot) {
  int s = slot ^ (row & 7);
  return *reinterpret_cast<const short8*>(lds + row * 64 + s * 8);
}

// out[M,N] = A[M,K](bf16) * W[N,K]^T(bf16); BMx128 tile, BK=64, 4 waves 2x2
// (wave tile BM/2 x 64). MODE 0: +bias -> bf16. 1: +bias,GELU -> bf16.
// 2: +bias += fp32 xres. 3: +bias,SiLU -> fp32 xres.
// mbound (nullable): device row bound; blocks with bm >= *mbound exit.
template <int MODE, int BM>
__global__ __launch_bounds__(256) void gemm_bf16(const u16* __restrict__ A,
                                                 const u16* __restrict__ W,
                                                 const float* __restrict__ bias,
                                                 float* __restrict__ xres,
                                                 u16* __restrict__ obf,
                                                 int N, int K,
                                                 int zsA, int zsW, int zsB, int zsO,
                                                 const int* __restrict__ mbound) {
  __shared__ u16 Asb[BM * 64];
  __shared__ u16 Wsb[128 * 64];
  constexpr int MI = BM / 32;                // M-frags per wave
  int bn = blockIdx.x * 128, bm = blockIdx.y * BM;
  if (mbound && bm >= *mbound) return;
  int z = blockIdx.z;
  if (z) {
    A += (size_t)z * zsA;
    W += (size_t)z * zsW;
    bias += (size_t)z * zsB;
    if (MODE == 2 || MODE == 3) xres += (size_t)z * zsO;
    else obf += (size_t)z * zsO;
  }
  int tid = threadIdx.x;
  int wave = tid >> 6, lane = tid & 63, lo = lane & 15, hi = lane >> 4;
  int wr = wave >> 1, wc = wave & 1;
  const u16* Ag = A + (size_t)bm * K;
  const u16* Wg = W + (size_t)bn * K;
  f32x4 acc[MI][4] = {};
  for (int k0 = 0; k0 < K; k0 += 64) {
    stage_tile<BM>(Ag + k0, K, Asb, tid);
    stage_tile<128>(Wg + k0, K, Wsb, tid);
    __syncthreads();
#pragma unroll
    for (int ks = 0; ks < 2; ++ks) {
      short8 a[MI], b[4];
#pragma unroll
      for (int mi = 0; mi < MI; ++mi)
        a[mi] = frag_ld(Asb, wr * (BM / 2) + mi * 16 + lo, ks * 4 + hi);
#pragma unroll
      for (int nj = 0; nj < 4; ++nj)
        b[nj] = frag_ld(Wsb, wc * 64 + nj * 16 + lo, ks * 4 + hi);
#pragma unroll
      for (int mi = 0; mi < MI; ++mi)
#pragma unroll
        for (int nj = 0; nj < 4; ++nj)
          acc[mi][nj] = __builtin_amdgcn_mfma_f32_16x16x32_bf16(a[mi], b[nj], acc[mi][nj], 0, 0, 0);
    }
    __syncthreads();
  }
  float bv[4];
#pragma unroll
  for (int nj = 0; nj < 4; ++nj) bv[nj] = bias[bn + wc * 64 + nj * 16 + lo];
#pragma unroll
  for (int mi = 0; mi < MI; ++mi) {
#pragma unroll
    for (int r = 0; r < 4; ++r) {
      int m = bm + wr * (BM / 2) + mi * 16 + hi * 4 + r;
#pragma unroll
      for (int nj = 0; nj < 4; ++nj) {
        int n = bn + wc * 64 + nj * 16 + lo;
        float v = acc[mi][nj][r] + bv[nj];
        size_t idx = (size_t)m * N + n;
        if (MODE == 0) {
          obf[idx] = f2bf(v);
        } else if (MODE == 1) {
          v = 0.5f * v * (1.f + erff(v * 0.70710678f));
          obf[idx] = f2bf(v);
        } else if (MODE == 2) {
          xres[idx] += v;
        } else {  // MODE 3
          xres[idx] = v / (1.f + expf(-v));
        }
      }
    }
  }
}

// ---------------- agent logit + threshold + ambiguity list (4 waves/block) ----
__global__ __launch_bounds__(256) void sel_kernel(const float* __restrict__ hidden,
                                                  const float* __restrict__ w2,
                                                  const float* __restrict__ b2,
                                                  int* __restrict__ sel,
                                                  int* __restrict__ ctr,
                                                  int* __restrict__ list) {
  int wv = threadIdx.x >> 6, t = threadIdx.x & 63;
  int row = blockIdx.x * 4 + wv;
  const float* hr = hidden + (size_t)row * HID;
  float s = 0.f;
#pragma unroll
  for (int i = 0; i < HID / 64; ++i) s += hr[t + i * 64] * w2[t + i * 64];
  for (int off = 32; off; off >>= 1) s += __shfl_down(s, off);
  if (t == 0) {
    float logit = s + b2[0];
    sel[row] = logit > 0.f ? 1 : 0;
    if (fabsf(logit) < 0.02f) {
      int idx = atomicAdd(ctr, 1);
      if (idx < FIXCAP) list[idx] = row;
    }
  }
}

// ------- fixup stage 1: per-(flagged row, 64-unit chunk) partial logit -------
__global__ __launch_bounds__(256) void fixup_part(const float* __restrict__ x0,
                                                  const float* __restrict__ x1,
                                                  const float* __restrict__ w1,
                                                  const float* __restrict__ b1,
                                                  const float* __restrict__ w2,
                                                  const int* __restrict__ ctr,
                                                  const int* __restrict__ list,
                                                  float* __restrict__ part) {
  __shared__ float xs[K2C];
  __shared__ float red[4];
  int cnt = ctr[0];
  if (cnt > FIXCAP) cnt = FIXCAP;
  int items = cnt * 8;
  int tid = threadIdx.x;
  f32x4* xsv = reinterpret_cast<f32x4*>(xs);
  for (int w = blockIdx.x; w < items; w += gridDim.x) {
    int ii = w >> 3, chunk = w & 7;
    int row = list[ii];
    if (tid < 96) xsv[tid] = reinterpret_cast<const f32x4*>(x0 + (size_t)row * C)[tid];
    else if (tid < 192)
      xsv[tid] = reinterpret_cast<const f32x4*>(x1 + (size_t)row * C)[tid - 96];
    __syncthreads();
    int n = chunk * 64 + (tid >> 2);   // hidden unit
    int q = tid & 3;                    // K quarter
    const f32x4* wr = reinterpret_cast<const f32x4*>(w1 + (size_t)n * K2C) + q * 48;
    const f32x4* xq = xsv + q * 48;
    float a0 = 0.f, a1 = 0.f, a2 = 0.f, a3 = 0.f;
#pragma unroll 12
    for (int k = 0; k < 48; ++k) {
      f32x4 wv = wr[k], xv = xq[k];
      a0 = fmaf(wv[0], xv[0], a0);
      a1 = fmaf(wv[1], xv[1], a1);
      a2 = fmaf(wv[2], xv[2], a2);
      a3 = fmaf(wv[3], xv[3], a3);
    }
    float d = (a0 + a1) + (a2 + a3);
    d += __shfl_xor(d, 1);
    d += __shfl_xor(d, 2);
    float pl = 0.f;
    if (q == 0) {
      float acc = d + b1[n];
      acc = acc / (1.f + expf(-acc));  // SiLU
      pl = acc * w2[n];
    }
    for (int off = 32; off; off >>= 1) pl += __shfl_down(pl, off);
    if ((tid & 63) == 0) red[tid >> 6] = pl;
    __syncthreads();
    if (tid == 0) part[w] = red[0] + red[1] + red[2] + red[3];
    __syncthreads();
  }
}

// ------- fixup stage 2: deterministic 8-way sum + sign decision -------
__global__ __launch_bounds__(64) void fixup_finish(const float* __restrict__ part,
                                                   const float* __restrict__ b2,
                                                   const int* __restrict__ ctr,
                                                   const int* __restrict__ list,
                                                   int* __restrict__ sel) {
  int ii = blockIdx.x * 64 + threadIdx.x;
  int cnt = ctr[0];
  if (cnt > FIXCAP) cnt = FIXCAP;
  if (ii >= cnt) return;
  float s = b2[0];
#pragma unroll
  for (int j = 0; j < 8; ++j) s += part[ii * 8 + j];
  sel[list[ii]] = s > 0.f ? 1 : 0;
}

// ---------------- per-batch exclusive prefix scan of sel ----------------
__global__ __launch_bounds__(256) void prefix_kernel(const int* __restrict__ sel,
                                                     int* __restrict__ pos,
                                                     int* __restrict__ nsel) {
  __shared__ int wsum[4];
  int b = blockIdx.x, tid = threadIdx.x;
  int lane = tid & 63, wv = tid >> 6;
  int v[4], lp[4];
  int tot = 0;
#pragma unroll
  for (int j = 0; j < 4; ++j) {
    v[j] = sel[b * S + tid * 4 + j];
    lp[j] = tot;
    tot += v[j];
  }
  int inc = tot;
#pragma unroll
  for (int off = 1; off < 64; off <<= 1) {
    int n = __shfl_up(inc, off);
    if (lane >= off) inc += n;
  }
  if (lane == 63) wsum[wv] = inc;
  __syncthreads();
  int wbase = 0;
#pragma unroll
  for (int w = 0; w < 4; ++w)
    if (w < wv) wbase += wsum[w];
  int ex = wbase + inc - tot;
#pragma unroll
  for (int j = 0; j < 4; ++j) pos[b * S + tid * 4 + j] = ex + lp[j];
  if (tid == 0) nsel[b] = wsum[0] + wsum[1] + wsum[2] + wsum[3];
}

// ---------------- per-batch 64-aligned compacted offsets ----------------
__global__ void boff_kernel(const int* __restrict__ nsel, int* __restrict__ coff) {
  if (threadIdx.x == 0) {
    int acc = 0;
    for (int b = 0; b < 8; ++b) {
      coff[b] = acc;
      acc += (nsel[b] + 63) & ~63;
    }
    coff[8] = acc;  // Mcp (64-aligned total compacted rows per stream)
  }
}

// ------- gather selected x rows into compacted xc (+ fused pad zeroing) ------
// Blocks [0, 2M/4): 4 rows each (1 wave per row). Tail 16 blocks: zero pads.
__global__ __launch_bounds__(256) void gather_x(const float* __restrict__ x0,
                                                const int* __restrict__ sel,
                                                const int* __restrict__ pos,
                                                const int* __restrict__ coff,
                                                const int* __restrict__ nsel,
                                                float* __restrict__ xc) {
  int bid = blockIdx.x;
  if (bid >= (2 * M) / 4) {
    int z = bid - (2 * M) / 4;          // 16 = 2 streams x 8 batches
    int strm = z >> 3, b = z & 7;
    int ns = nsel[b];
    int npad = ((ns + 63) & ~63) - ns;
    f32x4* base = reinterpret_cast<f32x4*>(
        xc + ((size_t)(strm * M) + coff[b] + ns) * C);
    int tot = npad * (C / 4);
    f32x4 zz = {};
    for (int i = threadIdx.x; i < tot; i += 256) base[i] = zz;
    return;
  }
  int wv = threadIdx.x >> 6, t = threadIdx.x & 63;
  int row = bid * 4 + wv;               // 0..2M
  int bs = row & (M - 1);
  if (!sel[bs]) return;
  int strm = row >> 13, b = bs >> 10;
  int rc = coff[b] + pos[bs];
  const f32x4* src = reinterpret_cast<const f32x4*>(x0 + (size_t)row * C);
  f32x4* dst = reinterpret_cast<f32x4*>(xc + ((size_t)(strm * M) + rc) * C);
  dst[t] = src[t];
  if (t < 32) dst[t + 64] = src[t + 64];
}

// ------- compacted LayerNorm -> bf16, 4 rows/block (1 wave per row) -------
__global__ __launch_bounds__(256) void ln_kernel(const float* __restrict__ x,
                                                 const float* __restrict__ g_all,
                                                 const float* __restrict__ b_all,
                                                 u16* __restrict__ y,
                                                 const int* __restrict__ coff) {
  int wv = threadIdx.x >> 6, t = threadIdx.x & 63;
  int row = blockIdx.x * 4 + wv;
  int strm = row >> 13, rc = row & (M - 1);
  if (rc >= coff[8]) return;
  const float* g = g_all + strm * C;
  const float* bt = b_all + strm * C;
  const float* xr = x + (size_t)row * C;
  float v[C / 64];
  float s = 0.f, s2 = 0.f;
#pragma unroll
  for (int i = 0; i < C / 64; ++i) {
    float a = xr[t + i * 64];
    v[i] = a;
    s += a;
    s2 += a * a;
  }
  for (int off = 32; off; off >>= 1) {
    s += __shfl_down(s, off);
    s2 += __shfl_down(s2, off);
  }
  s = __shfl(s, 0);
  s2 = __shfl(s2, 0);
  float mean = s / C;
  float var = s2 / C - mean * mean;
  float inv = rsqrtf(var + 1e-5f);
#pragma unroll
  for (int i = 0; i < C / 64; ++i) {
    int c = t + i * 64;
    y[(size_t)row * C + c] = f2bf((v[i] - mean) * inv * g[c] + bt[c]);
  }
}

// ---------------- flash MFMA attention v6 (fully compacted rows) --------------
__global__ __launch_bounds__(256) void attn_mfma(const u16* __restrict__ qkvc,
                                                 const int* __restrict__ nsel,
                                                 const int* __restrict__ coff,
                                                 u16* __restrict__ Dc) {
  __shared__ u16 Ks[64][104];
  __shared__ u16 Vt[96][72];

  int bq0 = blockIdx.x * 64;
  int bh2 = blockIdx.y;                  // 64 = 2 streams x 8 b x 4 h
  int strm = bh2 >> 5, bh = bh2 & 31;
  int b = bh >> 2, h = bh & 3;
  int ns = nsel[b];
  if (bq0 >= ns) return;
  int cb = coff[b];
  const u16* qbase = qkvc + ((size_t)(strm * M) + cb) * C3;
  int tid = threadIdx.x;
  int wave = tid >> 6, lane = tid & 63;
  int lo = lane & 15, g = lane >> 4;

  // Q fragments in registers, pre-scaled by 1/sqrt(HD)
  const float scale = 0.1020620726f;
  short8 bq[3];
  const u16* qrow = qbase + (size_t)(bq0 + wave * 16 + lo) * C3 + h * HD;
#pragma unroll
  for (int c = 0; c < 3; ++c) {
    short8 q = *reinterpret_cast<const short8*>(qrow + c * 32 + g * 8);
    short8 r;
#pragma unroll
    for (int e = 0; e < 8; ++e) r[e] = (short)f2bf(bf2f((u16)q[e]) * scale);
    bq[c] = r;
  }

  float m = -30.f, l = 0.f;
  f32x4 o[6] = {};
  int nt64 = (ns + 63) & ~63;

  for (int kt0 = 0; kt0 < nt64; kt0 += 64) {
    const u16* kbase = qbase + (size_t)kt0 * C3 + C + h * HD;
    const u16* vbase = qbase + (size_t)kt0 * C3 + 2 * C + h * HD;
#pragma unroll
    for (int i = 0; i < 3; ++i) {
      int idx = i * 256 + tid;
      int r = idx / 12, j = idx - r * 12;
      *reinterpret_cast<short8*>(&Ks[r][j * 8]) =
          *reinterpret_cast<const short8*>(kbase + (size_t)r * C3 + j * 8);
    }
#pragma unroll
    for (int i = 0; i < 3; ++i) {
      int idx = i * 256 + tid;
      int r = idx & 63, j = idx >> 6;
      short8 v = *reinterpret_cast<const short8*>(vbase + (size_t)r * C3 + j * 8);
#pragma unroll
      for (int e = 0; e < 8; ++e) Vt[j * 8 + e][r] = (u16)v[e];
    }
    __syncthreads();

    // QK^T: st[t4][r] = S[k=kt0+16t4+4g+r][q=lo]
    f32x4 st[4] = {};
    __builtin_amdgcn_s_setprio(1);
#pragma unroll
    for (int c = 0; c < 3; ++c)
#pragma unroll
      for (int t4 = 0; t4 < 4; ++t4) {
        short8 ak = *reinterpret_cast<const short8*>(&Ks[t4 * 16 + lo][c * 32 + g * 8]);
        st[t4] = __builtin_amdgcn_mfma_f32_16x16x32_bf16(ak, bq[c], st[t4], 0, 0, 0);
      }
    __builtin_amdgcn_s_setprio(0);

    float p[4][4];
    float pmax = -INFINITY;
#pragma unroll
    for (int t4 = 0; t4 < 4; ++t4)
#pragma unroll
      for (int r = 0; r < 4; ++r) p[t4][r] = st[t4][r];
    if (kt0 + 64 > ns) {  // tail tile: mask pad keys
#pragma unroll
      for (int t4 = 0; t4 < 4; ++t4)
#pragma unroll
        for (int r = 0; r < 4; ++r)
          if (kt0 + t4 * 16 + g * 4 + r >= ns) p[t4][r] = -1e9f;
    }
#pragma unroll
    for (int t4 = 0; t4 < 4; ++t4)
#pragma unroll
      for (int r = 0; r < 4; ++r) pmax = fmaxf(pmax, p[t4][r]);
    pmax = fmaxf(pmax, __shfl_xor(pmax, 16));
    pmax = fmaxf(pmax, __shfl_xor(pmax, 32));
    if (__any(pmax - m > 8.f)) {
      float mn = fmaxf(m, pmax);
      float sc = __expf(m - mn);
      m = mn;
      l *= sc;
#pragma unroll
      for (int dt = 0; dt < 6; ++dt)
#pragma unroll
        for (int r = 0; r < 4; ++r) o[dt][r] *= sc;
    }
    float ps = 0.f;
#pragma unroll
    for (int t4 = 0; t4 < 4; ++t4)
#pragma unroll
      for (int r = 0; r < 4; ++r) {
        float e = __expf(p[t4][r] - m);
        p[t4][r] = e;
        ps += e;
      }
    ps += __shfl_xor(ps, 16);
    ps += __shfl_xor(ps, 32);
    l += ps;

    // pack P -> bf16 B-fragments; slot e<4: k=32h2+4g+e, e>=4: k=32h2+16+4g+(e-4)
    short8 bp[2];
#pragma unroll
    for (int h2 = 0; h2 < 2; ++h2) {
      union { short8 s8; unsigned int u[4]; } u_;
      u_.u[0] = cvtpk(p[2 * h2][0], p[2 * h2][1]);
      u_.u[1] = cvtpk(p[2 * h2][2], p[2 * h2][3]);
      u_.u[2] = cvtpk(p[2 * h2 + 1][0], p[2 * h2 + 1][1]);
      u_.u[3] = cvtpk(p[2 * h2 + 1][2], p[2 * h2 + 1][3]);
      bp[h2] = u_.s8;
    }

    // PV: A = V^T with the same k-slot permutation
    __builtin_amdgcn_s_setprio(1);
#pragma unroll
    for (int dt = 0; dt < 6; ++dt)
#pragma unroll
      for (int h2 = 0; h2 < 2; ++h2) {
        union { short8 s8; short4 s4[2]; } a_;
        a_.s4[0] = *reinterpret_cast<const short4*>(&Vt[dt * 16 + lo][h2 * 32 + g * 4]);
        a_.s4[1] = *reinterpret_cast<const short4*>(&Vt[dt * 16 + lo][h2 * 32 + 16 + g * 4]);
        o[dt] = __builtin_amdgcn_mfma_f32_16x16x32_bf16(a_.s8, bp[h2], o[dt], 0, 0, 0);
      }
    __builtin_amdgcn_s_setprio(0);
    __syncthreads();
  }

  float inv = 1.f / l;
  size_t orow = ((size_t)(strm * M) + cb + bq0 + wave * 16 + lo) * C + h * HD;
#pragma unroll
  for (int dt = 0; dt < 6; ++dt)
#pragma unroll
    for (int r = 0; r < 4; ++r)
      Dc[orow + dt * 16 + g * 4 + r] = f2bf(o[dt][r] * inv);
}

// ---------------- final scatter with compaction indirection ----------------
__global__ __launch_bounds__(256) void final_kernel(const float* __restrict__ xc,
                                                    const int* __restrict__ sel,
                                                    const int* __restrict__ pos,
                                                    const int* __restrict__ coff,
                                                    const float* __restrict__ f_ir,
                                                    const float* __restrict__ f_vis,
                                                    float* __restrict__ out) {
  __shared__ float tile[32][33];
  int b = blockIdx.z;
  int s0 = blockIdx.x * 32, c0 = blockIdx.y * 32;
  int tx = threadIdx.x, ty = threadIdx.y;  // 32 x 8
  const int* selb = sel + b * S;
  const int* posb = pos + b * S;
  int cb = coff[b];
#pragma unroll
  for (int i = 0; i < 32; i += 8) {
    int s = s0 + ty + i;
    if (selb[s]) {
      size_t rc = cb + posb[s];
      tile[ty + i][tx] = xc[rc * C + c0 + tx] + xc[((size_t)M + rc) * C + c0 + tx];
    }
  }
  __syncthreads();
#pragma unroll
  for (int i = 0; i < 32; i += 8) {
    int c = c0 + ty + i, s = s0 + tx;
    size_t idx = ((size_t)(b * C + c)) * S + s;
    float v = selb[s] ? tile[tx][ty + i] : (f_ir[idx] + f_vis[idx]);
    out[idx] = v;
  }
}

}  // namespace

extern "C" void kernel_launch(void* const* d_in, const int* in_sizes, int n_in,
                              void* d_out, int out_size, void* d_ws, size_t ws_size,
                              hipStream_t stream) {
  const float* f_ir = (const float*)d_in[0];
  const float* f_vis = (const float*)d_in[1];
  const float* agent_w1 = (const float*)d_in[2];
  const float* agent_b1 = (const float*)d_in[3];
  const float* agent_w2 = (const float*)d_in[4];
  const float* agent_b2 = (const float*)d_in[5];
  const float* norm_g = (const float*)d_in[6];
  const float* norm_b = (const float*)d_in[7];
  const float* in_w = (const float*)d_in[8];
  const float* in_b = (const float*)d_in[9];
  const float* out_w = (const float*)d_in[10];
  const float* out_b = (const float*)d_in[11];
  const float* ffn_w1 = (const float*)d_in[12];
  const float* ffn_b1 = (const float*)d_in[13];
  const float* ffn_w2 = (const float*)d_in[14];
  const float* ffn_b2 = (const float*)d_in[15];
  float* out = (float*)d_out;

  constexpr size_t MS = (size_t)M * C;
  float* ws = (float*)d_ws;
  float* x0 = ws;                                  // fp32 [2M,C] full rows
  float* xc = x0 + 2 * MS;                         // fp32 [2M,C] compacted residual
  u16* Hc = (u16*)(xc + 2 * MS);                   // [2M,FFN] region (hosts aliases)
  u16* wb_in = Hc + (size_t)2 * M * FFN;           // 2*C3*C
  u16* wb_out = wb_in + 2 * C3 * C;                // 2*C*C
  u16* wb_f1 = wb_out + 2 * C * C;                 // 2*FFN*C
  u16* wb_f2 = wb_f1 + 2 * FFN * C;                // 2*C*FFN
  u16* w1b = wb_f2 + 2 * C * FFN;                  // HID*K2C
  int* sel = (int*)(w1b + HID * K2C);
  int* ctr = sel + M;
  int* fixlist = ctr + 1;
  int* pos = fixlist + FIXCAP;                     // [8][1024]
  int* nsel = pos + M;                             // [8]
  int* coff = nsel + 8;                            // [9]; coff[8] = Mcp
  float* part = (float*)(coff + 9);                // [FIXCAP*8] fixup partials
  // aliases inside Hc region (each dead before its successor is written):
  u16* Ahi = Hc;                                   // [M,768] agent act (dead after agent gemm)
  float* hiddenF = (float*)(Hc + (size_t)M * 768); // [M,HID] fp32 (dead after sel/fixup)
  u16* qkvc = Hc;                                  // [2M,C3] compacted QKV (dead before FFN1)
  u16* Dc = (u16*)x0;                              // [2M,C] bf16 (aliases x0 after gather)
  float* x1 = x0 + MS;

  // 0) all weights -> bf16 in one dispatch (also zeroes fixup ctr)
  cvt_all<<<(N4_ALL + 255) / 256, 256, 0, stream>>>(in_w, out_w, ffn_w1, ffn_w2,
                                                    agent_w1, wb_in, ctr);

  // 1) both transposes in one dispatch (fused agent bf16 activation emit)
  transpose_cs<<<dim3(S / 32, C / 32, 2 * B), dim3(32, 8), 0, stream>>>(
      f_ir, f_vis, x0, Ahi);

  // 2) agent hidden: single-pass bf16 MFMA + SiLU, BM=64 (2 blocks/CU)
  gemm_bf16<3, 64><<<dim3(HID / 128, M / 64), 256, 0, stream>>>(
      Ahi, w1b, agent_b1, hiddenF, nullptr, HID, K2C, 0, 0, 0, 0, nullptr);

  // 3) selection mask + exact fp32 fixup (2-stage, parallel) + compaction meta
  sel_kernel<<<M / 4, 256, 0, stream>>>(hiddenF, agent_w2, agent_b2, sel, ctr,
                                        fixlist);
  fixup_part<<<2048, 256, 0, stream>>>(x0, x1, agent_w1, agent_b1, agent_w2,
                                       ctr, fixlist, part);
  fixup_finish<<<FIXCAP / 64, 64, 0, stream>>>(part, agent_b2, ctr, fixlist, sel);
  prefix_kernel<<<B, 256, 0, stream>>>(sel, pos, nsel);
  boff_kernel<<<1, 64, 0, stream>>>(nsel, coff);

  // 4) gather selected rows -> compacted residual xc (pad zeroing fused)
  gather_x<<<(2 * M) / 4 + 16, 256, 0, stream>>>(x0, sel, pos, coff, nsel, xc);

  // 5) compacted mixer, both streams z-batched (early-exit beyond coff[8])
  ln_kernel<<<(2 * M) / 4, 256, 0, stream>>>(xc, norm_g, norm_b, Dc, coff);
  gemm_bf16<0, 128><<<dim3(C3 / 128, M / 128, 2), 256, 0, stream>>>(
      Dc, wb_in, in_b, nullptr, qkvc, C3, C, M * C, C3 * C, C3, M * C3, coff + 8);
  attn_mfma<<<dim3(S / 64, B * HEADS * 2), 256, 0, stream>>>(qkvc, nsel, coff, Dc);
  gemm_bf16<2, 64><<<dim3(C / 128, M / 64, 2), 256, 0, stream>>>(
      Dc, wb_out, out_b, xc, nullptr, C, C, M * C, C * C, C, M * C, coff + 8);
  ln_kernel<<<(2 * M) / 4, 256, 0, stream>>>(xc, norm_g, norm_b, Dc, coff);
  gemm_bf16<1, 128><<<dim3(FFN / 128, M / 128, 2), 256, 0, stream>>>(
      Dc, wb_f1, ffn_b1, nullptr, Hc, FFN, C, M * C, FFN * C, FFN, M * FFN, coff + 8);
  gemm_bf16<2, 64><<<dim3(C / 128, M / 64, 2), 256, 0, stream>>>(
      Hc, wb_f2, ffn_b2, xc, nullptr, C, FFN, M * FFN, C * FFN, C, M * C, coff + 8);

  // 6) final scatter back to [B,C,H,W]
  final_kernel<<<dim3(S / 32, C / 32, B), dim3(32, 8), 0, stream>>>(
      xc, sel, pos, coff, f_ir, f_vis, out);
}